// Round 6
// baseline (661.512 us; speedup 1.0000x reference)
//
#include <hip/hip_runtime.h>
#include <hip/hip_fp16.h>
#include <math.h>

#define NNODES 20000
#define NEDGES 320000
#define CC 128          // channels
#define TC 384          // 3*C
#define BB 20           // basis dim
#define RCUT_F 5.0f
#define PI_F 3.14159265358979323846f
#define PKF 28          // packed floats per edge (112 B, float4-aligned)

// ---------------------------------------------------------------------------
// CSR build: zero -> histogram -> single-block scan -> pack+scatter
// ---------------------------------------------------------------------------
__global__ __launch_bounds__(256) void zero_counts_kernel(int* __restrict__ counts) {
  const int i = blockIdx.x * 256 + threadIdx.x;
  if (i < NNODES) counts[i] = 0;
}

__global__ __launch_bounds__(256) void hist_kernel(const int* __restrict__ eidx,
                                                   int* __restrict__ counts) {
  const int e = blockIdx.x * 256 + threadIdx.x;
  if (e < NEDGES) atomicAdd(&counts[eidx[e]], 1);
}

__global__ __launch_bounds__(512) void scan_kernel(int* __restrict__ counts,
                                                   int* __restrict__ offsets) {
  __shared__ int sums[512];
  const int t = threadIdx.x;
  const int chunk = 40;                       // ceil(20000/512)
  const int lo = t * chunk;
  const int hi = min(lo + chunk, NNODES);
  int s = 0;
  for (int i = lo; i < hi; ++i) s += counts[i];
  sums[t] = s;
  __syncthreads();
  for (int d = 1; d < 512; d <<= 1) {
    const int other = (t >= d) ? sums[t - d] : 0;
    __syncthreads();
    sums[t] += other;
    __syncthreads();
  }
  int run = sums[t] - s;                      // exclusive prefix
  for (int i = lo; i < hi; ++i) {
    offsets[i] = run;
    run += counts[i];
    counts[i] = 0;                            // re-zero: reused as scatter cursor
  }
  if (hi == NNODES) offsets[NNODES] = run;    // == NEDGES
}

// packed[pos] = { j(bits), fc, v0, v1, v2, fc*attrs[0..19], pad[3] }
__global__ __launch_bounds__(256) void pack_scatter_kernel(
    const int* __restrict__ eidx, const float* __restrict__ ew,
    const float* __restrict__ evers, const float* __restrict__ eattr,
    const int* __restrict__ offsets, int* __restrict__ counts,
    float* __restrict__ packed) {
  const int e = blockIdx.x * 256 + threadIdx.x;
  if (e >= NEDGES) return;
  const int i = eidx[e];
  const int j = eidx[NEDGES + e];
  const int pos = offsets[i] + atomicAdd(&counts[i], 1);
  const float w = ew[e];
  const float fc = (w < RCUT_F)
      ? 0.5f * (cosf(PI_F * (1.0f / RCUT_F) * w) + 1.0f) : 0.0f;
  float* p = packed + (size_t)pos * PKF;
  p[0] = __int_as_float(j);
  p[1] = fc;
  p[2] = evers[(size_t)e * 3];
  p[3] = evers[(size_t)e * 3 + 1];
  p[4] = evers[(size_t)e * 3 + 2];
  const float* ae = eattr + (size_t)e * BB;
  #pragma unroll
  for (int b = 0; b < BB; ++b) p[5 + b] = fc * ae[b];
}

// fp16 copy of mu for the gather's random-row reads (halves gather bytes).
__global__ __launch_bounds__(256) void mu2h_kernel(const float* __restrict__ mu,
                                                   __half* __restrict__ muh) {
  const int i = blockIdx.x * 256 + threadIdx.x;        // quad index
  if (i < NNODES * TC / 4) {
    const float4 v = reinterpret_cast<const float4*>(mu)[i];
    __half2* o = reinterpret_cast<__half2*>(muh) + (size_t)i * 2;
    o[0] = __floats2half2_rn(v.x, v.y);
    o[1] = __floats2half2_rn(v.z, v.w);
  }
}

// fallback (no packing) scatter for small ws
__global__ __launch_bounds__(256) void scatter_kernel(const int* __restrict__ eidx,
                                                      const int* __restrict__ offsets,
                                                      int* __restrict__ counts,
                                                      int* __restrict__ edge_list) {
  const int e = blockIdx.x * 256 + threadIdx.x;
  if (e < NEDGES) {
    const int i = eidx[e];
    const int pos = offsets[i] + atomicAdd(&counts[i], 1);
    edge_list[pos] = e;
  }
}

// ---------------------------------------------------------------------------
// Context net: x = silu(q@W1 + b1) @ W2 + b2      [N, 3C]  (stored as fp16)
// ---------------------------------------------------------------------------
#define CNPB 8
__global__ __launch_bounds__(128) void ctx_net_kernel(
    const float* __restrict__ q,
    const float* __restrict__ W1, const float* __restrict__ b1,
    const float* __restrict__ W2, const float* __restrict__ b2,
    __half* __restrict__ x) {
  __shared__ __align__(16) float q_lds[CNPB][CC];
  __shared__ __align__(16) float h_lds[CNPB][CC];
  const int t = threadIdx.x;
  const int node0 = blockIdx.x * CNPB;

  #pragma unroll
  for (int n = 0; n < CNPB; ++n)
    q_lds[n][t] = q[(size_t)(node0 + n) * CC + t];
  __syncthreads();

  float acc[CNPB];
  {
    const float bv = b1[t];
    #pragma unroll
    for (int n = 0; n < CNPB; ++n) acc[n] = bv;
  }
  for (int k = 0; k < CC; k += 8) {
    float w[8];
    #pragma unroll
    for (int r = 0; r < 8; ++r) w[r] = W1[(size_t)(k + r) * CC + t];
    #pragma unroll
    for (int n = 0; n < CNPB; ++n) {
      const float4 q0 = *reinterpret_cast<const float4*>(&q_lds[n][k]);
      const float4 q1 = *reinterpret_cast<const float4*>(&q_lds[n][k + 4]);
      acc[n] = fmaf(q0.x, w[0], acc[n]); acc[n] = fmaf(q0.y, w[1], acc[n]);
      acc[n] = fmaf(q0.z, w[2], acc[n]); acc[n] = fmaf(q0.w, w[3], acc[n]);
      acc[n] = fmaf(q1.x, w[4], acc[n]); acc[n] = fmaf(q1.y, w[5], acc[n]);
      acc[n] = fmaf(q1.z, w[6], acc[n]); acc[n] = fmaf(q1.w, w[7], acc[n]);
    }
  }
  #pragma unroll
  for (int n = 0; n < CNPB; ++n) {
    const float v = acc[n];
    h_lds[n][t] = v / (1.0f + expf(-v));
  }
  __syncthreads();

  float y0[CNPB], y1[CNPB], y2[CNPB];
  {
    const float bb0 = b2[t], bb1 = b2[CC + t], bb2 = b2[2 * CC + t];
    #pragma unroll
    for (int n = 0; n < CNPB; ++n) { y0[n] = bb0; y1[n] = bb1; y2[n] = bb2; }
  }
  for (int k = 0; k < CC; k += 8) {
    float w0[8], w1[8], w2[8];
    #pragma unroll
    for (int r = 0; r < 8; ++r) {
      const size_t row = (size_t)(k + r) * TC;
      w0[r] = W2[row + t];
      w1[r] = W2[row + CC + t];
      w2[r] = W2[row + 2 * CC + t];
    }
    #pragma unroll
    for (int n = 0; n < CNPB; ++n) {
      const float4 h0 = *reinterpret_cast<const float4*>(&h_lds[n][k]);
      const float4 h1 = *reinterpret_cast<const float4*>(&h_lds[n][k + 4]);
      y0[n] = fmaf(h0.x, w0[0], y0[n]); y0[n] = fmaf(h0.y, w0[1], y0[n]);
      y0[n] = fmaf(h0.z, w0[2], y0[n]); y0[n] = fmaf(h0.w, w0[3], y0[n]);
      y0[n] = fmaf(h1.x, w0[4], y0[n]); y0[n] = fmaf(h1.y, w0[5], y0[n]);
      y0[n] = fmaf(h1.z, w0[6], y0[n]); y0[n] = fmaf(h1.w, w0[7], y0[n]);
      y1[n] = fmaf(h0.x, w1[0], y1[n]); y1[n] = fmaf(h0.y, w1[1], y1[n]);
      y1[n] = fmaf(h0.z, w1[2], y1[n]); y1[n] = fmaf(h0.w, w1[3], y1[n]);
      y1[n] = fmaf(h1.x, w1[4], y1[n]); y1[n] = fmaf(h1.y, w1[5], y1[n]);
      y1[n] = fmaf(h1.z, w1[6], y1[n]); y1[n] = fmaf(h1.w, w1[7], y1[n]);
      y2[n] = fmaf(h0.x, w2[0], y2[n]); y2[n] = fmaf(h0.y, w2[1], y2[n]);
      y2[n] = fmaf(h0.z, w2[2], y2[n]); y2[n] = fmaf(h0.w, w2[3], y2[n]);
      y2[n] = fmaf(h1.x, w2[4], y2[n]); y2[n] = fmaf(h1.y, w2[5], y2[n]);
      y2[n] = fmaf(h1.z, w2[6], y2[n]); y2[n] = fmaf(h1.w, w2[7], y2[n]);
    }
  }
  #pragma unroll
  for (int n = 0; n < CNPB; ++n) {
    const size_t base = (size_t)(node0 + n) * TC;
    x[base + t]          = __float2half_rn(y0[n]);
    x[base + CC + t]     = __float2half_rn(y1[n]);
    x[base + 2 * CC + t] = __float2half_rn(y2[n]);
  }
}

// ---------------------------------------------------------------------------
// Gather (packed path): one block of 384 threads per node; thread c owns
// filter column c (weights in 20 regs).
// r5 post-mortem: fp16 halved FETCH (506->271 MB) but dur only 186->177 us
// => latency/issue-bound, not BW-bound. VGPR_Count was 24 (SGPR 80): the
// packed rows were scalarized and the vector file was too small to keep even
// 2 full chains in flight. Fix: unroll x4 in the r3 STYLE (all loads issued
// in one iteration body, compute after, NO manual rotate -- r4's rotate
// forced vmcnt(0) drains and regressed 186->294). 4 independent chains/wave.
// ---------------------------------------------------------------------------
#define GTH 384

struct EdgeRegs { float4 h0, h1, h2, h3, h4, h5, h6; };

__device__ __forceinline__ EdgeRegs load_edge(const float4* __restrict__ p4,
                                              int k) {
  const float4* p = p4 + (size_t)k * (PKF / 4);
  EdgeRegs E;
  E.h0 = p[0]; E.h1 = p[1]; E.h2 = p[2]; E.h3 = p[3];
  E.h4 = p[4]; E.h5 = p[5]; E.h6 = p[6];
  return E;
}

__device__ __forceinline__ float filter_ws(const EdgeRegs& E,
                                           const float* wreg, float bfc) {
  float ws = E.h0.y * bfc;                    // fc * bf[c]
  ws = fmaf(E.h1.y, wreg[0], ws);  ws = fmaf(E.h1.z, wreg[1], ws);
  ws = fmaf(E.h1.w, wreg[2], ws);  ws = fmaf(E.h2.x, wreg[3], ws);
  ws = fmaf(E.h2.y, wreg[4], ws);  ws = fmaf(E.h2.z, wreg[5], ws);
  ws = fmaf(E.h2.w, wreg[6], ws);  ws = fmaf(E.h3.x, wreg[7], ws);
  ws = fmaf(E.h3.y, wreg[8], ws);  ws = fmaf(E.h3.z, wreg[9], ws);
  ws = fmaf(E.h3.w, wreg[10], ws); ws = fmaf(E.h4.x, wreg[11], ws);
  ws = fmaf(E.h4.y, wreg[12], ws); ws = fmaf(E.h4.z, wreg[13], ws);
  ws = fmaf(E.h4.w, wreg[14], ws); ws = fmaf(E.h5.x, wreg[15], ws);
  ws = fmaf(E.h5.y, wreg[16], ws); ws = fmaf(E.h5.z, wreg[17], ws);
  ws = fmaf(E.h5.w, wreg[18], ws); ws = fmaf(E.h6.x, wreg[19], ws);
  return ws;
}

__global__ __launch_bounds__(GTH) void gather_packed_kernel(
    const float* __restrict__ packed,
    const float* __restrict__ Wf, const float* __restrict__ bf,
    const __half* __restrict__ xh, const __half* __restrict__ muh,
    const float* __restrict__ mu_in,
    const float* __restrict__ q_in, const int* __restrict__ offsets,
    float* __restrict__ qout, float* __restrict__ muout) {
  __shared__ float red[3][CC];
  const int c = threadIdx.x;
  const int i = blockIdx.x;
  const int grp = c >> 7;          // wave-uniform
  const int ch = c & 127;

  float wreg[BB];
  #pragma unroll
  for (int b = 0; b < BB; ++b) wreg[b] = Wf[b * TC + c];
  const float bfc = bf[c];

  const float4* p4 = reinterpret_cast<const float4*>(packed);
  const int start = offsets[i];
  const int end = offsets[i + 1];
  float a0 = 0.f, a1 = 0.f, a2 = 0.f;

  int k = start;

  // ---- x4 main loop: 4 independent load chains per iteration ----
  for (; k + 3 < end; k += 4) {
    const EdgeRegs E0 = load_edge(p4, k);
    const EdgeRegs E1 = load_edge(p4, k + 1);
    const EdgeRegs E2 = load_edge(p4, k + 2);
    const EdgeRegs E3 = load_edge(p4, k + 3);
    const int j0 = __float_as_int(E0.h0.x);
    const int j1 = __float_as_int(E1.h0.x);
    const int j2 = __float_as_int(E2.h0.x);
    const int j3 = __float_as_int(E3.h0.x);
    const float x0 = __half2float(xh[(size_t)j0 * TC + c]);
    const float x1 = __half2float(xh[(size_t)j1 * TC + c]);
    const float x2 = __half2float(xh[(size_t)j2 * TC + c]);
    const float x3 = __half2float(xh[(size_t)j3 * TC + c]);
    float m00, m01, m02, m10, m11, m12, m20, m21, m22, m30, m31, m32;
    if (grp == 2) {
      const __half* p0 = muh + (size_t)j0 * TC + ch;
      const __half* p1 = muh + (size_t)j1 * TC + ch;
      const __half* p2 = muh + (size_t)j2 * TC + ch;
      const __half* p3 = muh + (size_t)j3 * TC + ch;
      m00 = __half2float(p0[0]); m01 = __half2float(p0[CC]); m02 = __half2float(p0[2 * CC]);
      m10 = __half2float(p1[0]); m11 = __half2float(p1[CC]); m12 = __half2float(p1[2 * CC]);
      m20 = __half2float(p2[0]); m21 = __half2float(p2[CC]); m22 = __half2float(p2[2 * CC]);
      m30 = __half2float(p3[0]); m31 = __half2float(p3[CC]); m32 = __half2float(p3[2 * CC]);
    }
    const float ws0 = filter_ws(E0, wreg, bfc);
    const float ws1 = filter_ws(E1, wreg, bfc);
    const float ws2 = filter_ws(E2, wreg, bfc);
    const float ws3 = filter_ws(E3, wreg, bfc);
    const float xv0 = x0 * ws0;
    const float xv1 = x1 * ws1;
    const float xv2 = x2 * ws2;
    const float xv3 = x3 * ws3;
    if (grp == 0) {
      a0 += (xv0 + xv1) + (xv2 + xv3);
    } else if (grp == 1) {
      a0 = fmaf(xv0, E0.h0.z, fmaf(xv1, E1.h0.z, fmaf(xv2, E2.h0.z, fmaf(xv3, E3.h0.z, a0))));
      a1 = fmaf(xv0, E0.h0.w, fmaf(xv1, E1.h0.w, fmaf(xv2, E2.h0.w, fmaf(xv3, E3.h0.w, a1))));
      a2 = fmaf(xv0, E0.h1.x, fmaf(xv1, E1.h1.x, fmaf(xv2, E2.h1.x, fmaf(xv3, E3.h1.x, a2))));
    } else {
      a0 = fmaf(xv0, m00, fmaf(xv1, m10, fmaf(xv2, m20, fmaf(xv3, m30, a0))));
      a1 = fmaf(xv0, m01, fmaf(xv1, m11, fmaf(xv2, m21, fmaf(xv3, m31, a1))));
      a2 = fmaf(xv0, m02, fmaf(xv1, m12, fmaf(xv2, m22, fmaf(xv3, m32, a2))));
    }
  }

  // ---- x2 tail ----
  for (; k + 1 < end; k += 2) {
    const EdgeRegs A = load_edge(p4, k);
    const EdgeRegs B = load_edge(p4, k + 1);
    const int jA = __float_as_int(A.h0.x);
    const int jB = __float_as_int(B.h0.x);
    const float xA = __half2float(xh[(size_t)jA * TC + c]);
    const float xB = __half2float(xh[(size_t)jB * TC + c]);
    float muA0, muA1, muA2, muB0, muB1, muB2;
    if (grp == 2) {
      const __half* mA = muh + (size_t)jA * TC + ch;
      const __half* mB = muh + (size_t)jB * TC + ch;
      muA0 = __half2float(mA[0]); muA1 = __half2float(mA[CC]); muA2 = __half2float(mA[2 * CC]);
      muB0 = __half2float(mB[0]); muB1 = __half2float(mB[CC]); muB2 = __half2float(mB[2 * CC]);
    }
    const float wsA = filter_ws(A, wreg, bfc);
    const float wsB = filter_ws(B, wreg, bfc);
    const float xvA = xA * wsA;
    const float xvB = xB * wsB;
    if (grp == 0) {
      a0 += xvA + xvB;
    } else if (grp == 1) {
      a0 = fmaf(xvA, A.h0.z, fmaf(xvB, B.h0.z, a0));
      a1 = fmaf(xvA, A.h0.w, fmaf(xvB, B.h0.w, a1));
      a2 = fmaf(xvA, A.h1.x, fmaf(xvB, B.h1.x, a2));
    } else {
      a0 = fmaf(xvA, muA0, fmaf(xvB, muB0, a0));
      a1 = fmaf(xvA, muA1, fmaf(xvB, muB1, a1));
      a2 = fmaf(xvA, muA2, fmaf(xvB, muB2, a2));
    }
  }

  // ---- x1 tail ----
  if (k < end) {
    const EdgeRegs A = load_edge(p4, k);
    const int jA = __float_as_int(A.h0.x);
    const float xA = __half2float(xh[(size_t)jA * TC + c]);
    const float wsA = filter_ws(A, wreg, bfc);
    const float xvA = xA * wsA;
    if (grp == 0) {
      a0 += xvA;
    } else if (grp == 1) {
      a0 = fmaf(xvA, A.h0.z, a0);
      a1 = fmaf(xvA, A.h0.w, a1);
      a2 = fmaf(xvA, A.h1.x, a2);
    } else {
      const __half* mA = muh + (size_t)jA * TC + ch;
      a0 = fmaf(xvA, __half2float(mA[0]), a0);
      a1 = fmaf(xvA, __half2float(mA[CC]), a1);
      a2 = fmaf(xvA, __half2float(mA[2 * CC]), a2);
    }
  }

  if (grp == 1) { red[0][ch] = a0; red[1][ch] = a1; red[2][ch] = a2; }
  __syncthreads();

  if (grp == 0) {
    qout[(size_t)i * CC + ch] = q_in[(size_t)i * CC + ch] + a0;
  } else if (grp == 2) {
    const size_t mb = (size_t)i * TC;
    muout[mb + ch]          = mu_in[mb + ch]          + red[0][ch] + a0;
    muout[mb + CC + ch]     = mu_in[mb + CC + ch]     + red[1][ch] + a1;
    muout[mb + 2 * CC + ch] = mu_in[mb + 2 * CC + ch] + red[2][ch] + a2;
  }
}

// fallback gather (edge_list indirection) for small ws
__global__ __launch_bounds__(GTH) void gather_list_kernel(
    const int* __restrict__ eidx, const float* __restrict__ ew,
    const float* __restrict__ evers, const float* __restrict__ eattr,
    const float* __restrict__ Wf, const float* __restrict__ bf,
    const __half* __restrict__ xh, const float* __restrict__ mu_in,
    const float* __restrict__ q_in,
    const int* __restrict__ offsets, const int* __restrict__ edge_list,
    float* __restrict__ qout, float* __restrict__ muout) {
  __shared__ float red[3][CC];
  const int c = threadIdx.x;
  const int i = blockIdx.x;
  const int grp = c >> 7;
  const int ch = c & 127;
  float wreg[BB];
  #pragma unroll
  for (int b = 0; b < BB; ++b) wreg[b] = Wf[b * TC + c];
  const float bfc = bf[c];
  const int start = offsets[i];
  const int end = offsets[i + 1];
  float a0 = 0.f, a1 = 0.f, a2 = 0.f;
  for (int k = start; k < end; ++k) {
    const int e = edge_list[k];
    const int j = eidx[NEDGES + e];
    const float w = ew[e];
    const float fc = (w < RCUT_F)
        ? 0.5f * (cosf(PI_F * (1.0f / RCUT_F) * w) + 1.0f) : 0.0f;
    const float2* ae2 = reinterpret_cast<const float2*>(eattr + (size_t)e * BB);
    float wsum = bfc;
    #pragma unroll
    for (int b = 0; b < BB / 2; ++b) {
      const float2 a = ae2[b];
      wsum = fmaf(a.x, wreg[2 * b], wsum);
      wsum = fmaf(a.y, wreg[2 * b + 1], wsum);
    }
    wsum *= fc;
    const float xv = __half2float(xh[(size_t)j * TC + c]) * wsum;
    if (grp == 0) {
      a0 += xv;
    } else if (grp == 1) {
      const float v0 = evers[(size_t)e * 3];
      const float v1 = evers[(size_t)e * 3 + 1];
      const float v2 = evers[(size_t)e * 3 + 2];
      a0 = fmaf(xv, v0, a0); a1 = fmaf(xv, v1, a1); a2 = fmaf(xv, v2, a2);
    } else {
      const float* muj = mu_in + (size_t)j * TC + ch;
      a0 = fmaf(xv, muj[0], a0);
      a1 = fmaf(xv, muj[CC], a1);
      a2 = fmaf(xv, muj[2 * CC], a2);
    }
  }
  if (grp == 1) { red[0][ch] = a0; red[1][ch] = a1; red[2][ch] = a2; }
  __syncthreads();
  if (grp == 0) {
    qout[(size_t)i * CC + ch] = q_in[(size_t)i * CC + ch] + a0;
  } else if (grp == 2) {
    const size_t mb = (size_t)i * TC;
    muout[mb + ch]          = mu_in[mb + ch]          + red[0][ch] + a0;
    muout[mb + CC + ch]     = mu_in[mb + CC + ch]     + red[1][ch] + a1;
    muout[mb + 2 * CC + ch] = mu_in[mb + 2 * CC + ch] + red[2][ch] + a2;
  }
}

// ---------------------------------------------------------------------------
// Mixing kernel v4 (verified r3/r5): LDS-staged mu, 20 KB LDS, no spill.
// VGPR-allocator model (verified r0-r3): cap = f(LDS-implied occupancy).
// 20KB -> 8 blk/CU = 4 waves/SIMD -> cap 128 >= ~90 needed => no spill.
// ---------------------------------------------------------------------------
#define MNPB 8
__global__ __launch_bounds__(128) void mix_kernel(
    const float* __restrict__ Wmix, const float* __restrict__ Wm1,
    const float* __restrict__ bm1, const float* __restrict__ Wm2,
    const float* __restrict__ bm2, float* __restrict__ qout,
    float* __restrict__ muout) {
  __shared__ __align__(16) float mu_lds[MNPB][3][CC];   // 12 KB
  __shared__ __align__(16) float vn_lds[MNPB][CC];      // 4 KB
  __shared__ __align__(16) float h2_lds[MNPB][CC];      // 4 KB

  const int t = threadIdx.x;
  const int node0 = blockIdx.x * MNPB;

  #pragma unroll
  for (int n = 0; n < MNPB; ++n) {
    const size_t mb = (size_t)(node0 + n) * TC;
    mu_lds[n][0][t] = muout[mb + t];
    mu_lds[n][1][t] = muout[mb + CC + t];
    mu_lds[n][2][t] = muout[mb + 2 * CC + t];
  }
  __syncthreads();

  // ---- phase 1: mu_mix from LDS-staged mu ----
  float mW[MNPB][3], sdot[MNPB];
  {
    float mV[MNPB][3];
    #pragma unroll
    for (int n = 0; n < MNPB; ++n)
      #pragma unroll
      for (int v = 0; v < 3; ++v) { mV[n][v] = 0.0f; mW[n][v] = 0.0f; }

    for (int c = 0; c < CC; c += 8) {
      float wv[8], ww[8];
      #pragma unroll
      for (int r = 0; r < 8; ++r) {
        const size_t row = (size_t)(c + r) * (2 * CC);
        wv[r] = Wmix[row + t];
        ww[r] = Wmix[row + CC + t];
      }
      #pragma unroll
      for (int n = 0; n < MNPB; ++n) {
        #pragma unroll
        for (int v = 0; v < 3; ++v) {
          const float4 m0 = *reinterpret_cast<const float4*>(&mu_lds[n][v][c]);
          const float4 m1 = *reinterpret_cast<const float4*>(&mu_lds[n][v][c + 4]);
          float a = mV[n][v], b = mW[n][v];
          a = fmaf(m0.x, wv[0], a); a = fmaf(m0.y, wv[1], a);
          a = fmaf(m0.z, wv[2], a); a = fmaf(m0.w, wv[3], a);
          a = fmaf(m1.x, wv[4], a); a = fmaf(m1.y, wv[5], a);
          a = fmaf(m1.z, wv[6], a); a = fmaf(m1.w, wv[7], a);
          b = fmaf(m0.x, ww[0], b); b = fmaf(m0.y, ww[1], b);
          b = fmaf(m0.z, ww[2], b); b = fmaf(m0.w, ww[3], b);
          b = fmaf(m1.x, ww[4], b); b = fmaf(m1.y, ww[5], b);
          b = fmaf(m1.z, ww[6], b); b = fmaf(m1.w, ww[7], b);
          mV[n][v] = a; mW[n][v] = b;
        }
      }
    }
    #pragma unroll
    for (int n = 0; n < MNPB; ++n) {
      const float ss = mV[n][0] * mV[n][0] + mV[n][1] * mV[n][1] + mV[n][2] * mV[n][2];
      vn_lds[n][t] = sqrtf(ss + 1e-8f);
      sdot[n] = mV[n][0] * mW[n][0] + mV[n][1] * mW[n][1] + mV[n][2] * mW[n][2];
    }
  } // mV dies here
  __syncthreads();   // vn_lds visible

  // ---- phase 2: silu(ctx @ Wm1 + bm1) ----
  float acc[MNPB];
  {
    const float bv = bm1[t];
    #pragma unroll
    for (int n = 0; n < MNPB; ++n) acc[n] = bv;
  }
  // ctx first half: q, wave-uniform broadcast from global (L3-hot)
  for (int k = 0; k < CC; k += 8) {
    float w[8];
    #pragma unroll
    for (int r = 0; r < 8; ++r) w[r] = Wm1[(size_t)(k + r) * CC + t];
    #pragma unroll
    for (int n = 0; n < MNPB; ++n) {
      const float* qrow = qout + (size_t)(node0 + n) * CC + k;
      const float4 c0 = *reinterpret_cast<const float4*>(qrow);
      const float4 c1 = *reinterpret_cast<const float4*>(qrow + 4);
      acc[n] = fmaf(c0.x, w[0], acc[n]); acc[n] = fmaf(c0.y, w[1], acc[n]);
      acc[n] = fmaf(c0.z, w[2], acc[n]); acc[n] = fmaf(c0.w, w[3], acc[n]);
      acc[n] = fmaf(c1.x, w[4], acc[n]); acc[n] = fmaf(c1.y, w[5], acc[n]);
      acc[n] = fmaf(c1.z, w[6], acc[n]); acc[n] = fmaf(c1.w, w[7], acc[n]);
    }
  }
  // ctx second half: mu_Vn from LDS (broadcast)
  for (int k = 0; k < CC; k += 8) {
    float w[8];
    #pragma unroll
    for (int r = 0; r < 8; ++r) w[r] = Wm1[(size_t)(CC + k + r) * CC + t];
    #pragma unroll
    for (int n = 0; n < MNPB; ++n) {
      const float4 c0 = *reinterpret_cast<const float4*>(&vn_lds[n][k]);
      const float4 c1 = *reinterpret_cast<const float4*>(&vn_lds[n][k + 4]);
      acc[n] = fmaf(c0.x, w[0], acc[n]); acc[n] = fmaf(c0.y, w[1], acc[n]);
      acc[n] = fmaf(c0.z, w[2], acc[n]); acc[n] = fmaf(c0.w, w[3], acc[n]);
      acc[n] = fmaf(c1.x, w[4], acc[n]); acc[n] = fmaf(c1.y, w[5], acc[n]);
      acc[n] = fmaf(c1.z, w[6], acc[n]); acc[n] = fmaf(c1.w, w[7], acc[n]);
    }
  }
  #pragma unroll
  for (int n = 0; n < MNPB; ++n) {
    const float v = acc[n];
    h2_lds[n][t] = v / (1.0f + expf(-v));
  }
  __syncthreads();   // h2 visible; all phase-2 broadcast reads of qout done

  // ---- phase 3: y = h2 @ Wm2 + bm2 ----
  float y0[MNPB], y1[MNPB], y2[MNPB];
  {
    const float bb0 = bm2[t], bb1 = bm2[CC + t], bb2 = bm2[2 * CC + t];
    #pragma unroll
    for (int n = 0; n < MNPB; ++n) { y0[n] = bb0; y1[n] = bb1; y2[n] = bb2; }
  }
  for (int k = 0; k < CC; k += 8) {
    float w0[8], w1[8], w2[8];
    #pragma unroll
    for (int r = 0; r < 8; ++r) {
      const size_t row = (size_t)(k + r) * TC;
      w0[r] = Wm2[row + t];
      w1[r] = Wm2[row + CC + t];
      w2[r] = Wm2[row + 2 * CC + t];
    }
    #pragma unroll
    for (int n = 0; n < MNPB; ++n) {
      const float4 h0 = *reinterpret_cast<const float4*>(&h2_lds[n][k]);
      const float4 h1 = *reinterpret_cast<const float4*>(&h2_lds[n][k + 4]);
      y0[n] = fmaf(h0.x, w0[0], y0[n]); y0[n] = fmaf(h0.y, w0[1], y0[n]);
      y0[n] = fmaf(h0.z, w0[2], y0[n]); y0[n] = fmaf(h0.w, w0[3], y0[n]);
      y0[n] = fmaf(h1.x, w0[4], y0[n]); y0[n] = fmaf(h1.y, w0[5], y0[n]);
      y0[n] = fmaf(h1.z, w0[6], y0[n]); y0[n] = fmaf(h1.w, w0[7], y0[n]);
      y1[n] = fmaf(h0.x, w1[0], y1[n]); y1[n] = fmaf(h0.y, w1[1], y1[n]);
      y1[n] = fmaf(h0.z, w1[2], y1[n]); y1[n] = fmaf(h0.w, w1[3], y1[n]);
      y1[n] = fmaf(h1.x, w1[4], y1[n]); y1[n] = fmaf(h1.y, w1[5], y1[n]);
      y1[n] = fmaf(h1.z, w1[6], y1[n]); y1[n] = fmaf(h1.w, w1[7], y1[n]);
      y2[n] = fmaf(h0.x, w2[0], y2[n]); y2[n] = fmaf(h0.y, w2[1], y2[n]);
      y2[n] = fmaf(h0.z, w2[2], y2[n]); y2[n] = fmaf(h0.w, w2[3], y2[n]);
      y2[n] = fmaf(h1.x, w2[4], y2[n]); y2[n] = fmaf(h1.y, w2[5], y2[n]);
      y2[n] = fmaf(h1.z, w2[6], y2[n]); y2[n] = fmaf(h1.w, w2[7], y2[n]);
    }
  }

  // ---- epilogue: q re-read coalesced (L3-hot), mu residual from LDS ----
  #pragma unroll
  for (int n = 0; n < MNPB; ++n) {
    const size_t qb = (size_t)(node0 + n) * CC;
    qout[qb + t] = qout[qb + t] + y0[n] + y2[n] * sdot[n];
    const size_t mb = (size_t)(node0 + n) * TC;
    muout[mb + t]          = mu_lds[n][0][t] + y1[n] * mW[n][0];
    muout[mb + CC + t]     = mu_lds[n][1][t] + y1[n] * mW[n][1];
    muout[mb + 2 * CC + t] = mu_lds[n][2][t] + y1[n] * mW[n][2];
  }
}

// ---------------------------------------------------------------------------
extern "C" void kernel_launch(void* const* d_in, const int* in_sizes, int n_in,
                              void* d_out, int out_size, void* d_ws, size_t ws_size,
                              hipStream_t stream) {
  const float* q     = (const float*)d_in[0];
  const float* mu    = (const float*)d_in[1];
  const int*   eidx  = (const int*)d_in[2];
  const float* ew    = (const float*)d_in[3];
  const float* evers = (const float*)d_in[4];
  const float* eattr = (const float*)d_in[5];
  const float* Wf    = (const float*)d_in[6];
  const float* bf    = (const float*)d_in[7];
  const float* W1    = (const float*)d_in[8];
  const float* b1    = (const float*)d_in[9];
  const float* W2    = (const float*)d_in[10];
  const float* b2    = (const float*)d_in[11];
  const float* Wmix  = (const float*)d_in[12];
  const float* Wm1   = (const float*)d_in[13];
  const float* bm1   = (const float*)d_in[14];
  const float* Wm2   = (const float*)d_in[15];
  const float* bm2   = (const float*)d_in[16];

  float* out   = (float*)d_out;
  float* qout  = out;                                // [N, C]
  float* muout = out + (size_t)NNODES * CC;          // [N, 3, C]

  // workspace layout: packed | xh (fp16) | muh (fp16) | counts | offsets
  float*  packed  = (float*)d_ws;                           // [E*28] floats
  __half* xh      = (__half*)(packed + (size_t)NEDGES * PKF);   // [N*3C] halves
  __half* muh     = xh + (size_t)NNODES * TC;                   // [N*3C] halves
  int*    counts  = (int*)(muh + (size_t)NNODES * TC);      // [N]
  int*    offsets = counts + NNODES;                        // [N+1]
  const size_t need_packed =
      (size_t)NEDGES * PKF * 4 + (size_t)NNODES * TC * 2 * 2 +
      (2 * NNODES + 2) * 4 + 256;
  const bool use_packed = ws_size >= need_packed;

  if (use_packed) {
    zero_counts_kernel<<<(NNODES + 255) / 256, 256, 0, stream>>>(counts);
    hist_kernel<<<(NEDGES + 255) / 256, 256, 0, stream>>>(eidx, counts);
    scan_kernel<<<1, 512, 0, stream>>>(counts, offsets);
    pack_scatter_kernel<<<(NEDGES + 255) / 256, 256, 0, stream>>>(
        eidx, ew, evers, eattr, offsets, counts, packed);
    mu2h_kernel<<<(NNODES * TC / 4 + 255) / 256, 256, 0, stream>>>(mu, muh);
    ctx_net_kernel<<<NNODES / CNPB, 128, 0, stream>>>(q, W1, b1, W2, b2, xh);
    gather_packed_kernel<<<NNODES, GTH, 0, stream>>>(
        packed, Wf, bf, xh, muh, mu, q, offsets, qout, muout);
  } else {
    // fallback layout (xh fp16 | counts | offsets | edge_list)
    __half* xf       = (__half*)d_ws;
    int*   countsf   = (int*)(xf + (size_t)NNODES * TC);
    int*   offsetsf  = countsf + NNODES;
    int*   edge_list = offsetsf + NNODES + 1;
    zero_counts_kernel<<<(NNODES + 255) / 256, 256, 0, stream>>>(countsf);
    hist_kernel<<<(NEDGES + 255) / 256, 256, 0, stream>>>(eidx, countsf);
    scan_kernel<<<1, 512, 0, stream>>>(countsf, offsetsf);
    scatter_kernel<<<(NEDGES + 255) / 256, 256, 0, stream>>>(eidx, offsetsf,
                                                             countsf, edge_list);
    ctx_net_kernel<<<NNODES / CNPB, 128, 0, stream>>>(q, W1, b1, W2, b2, xf);
    gather_list_kernel<<<NNODES, GTH, 0, stream>>>(eidx, ew, evers, eattr,
                                                   Wf, bf, xf, mu, q,
                                                   offsetsf, edge_list,
                                                   qout, muout);
  }
  mix_kernel<<<NNODES / MNPB, 128, 0, stream>>>(Wmix, Wm1, bm1, Wm2, bm2,
                                                qout, muout);
}

// Round 7
// 658.146 us; speedup vs baseline: 1.0051x; 1.0051x over previous
//
#include <hip/hip_runtime.h>
#include <hip/hip_fp16.h>
#include <math.h>

#define NNODES 20000
#define NEDGES 320000
#define CC 128          // channels
#define TC 384          // 3*C
#define BB 20           // basis dim
#define RCUT_F 5.0f
#define PI_F 3.14159265358979323846f
#define PKF 28          // packed floats per edge (112 B, float4-aligned)

// ---------------------------------------------------------------------------
// CSR build: zero -> histogram -> single-block scan -> pack+scatter
// ---------------------------------------------------------------------------
__global__ __launch_bounds__(256) void zero_counts_kernel(int* __restrict__ counts) {
  const int i = blockIdx.x * 256 + threadIdx.x;
  if (i < NNODES) counts[i] = 0;
}

__global__ __launch_bounds__(256) void hist_kernel(const int* __restrict__ eidx,
                                                   int* __restrict__ counts) {
  const int e = blockIdx.x * 256 + threadIdx.x;
  if (e < NEDGES) atomicAdd(&counts[eidx[e]], 1);
}

__global__ __launch_bounds__(512) void scan_kernel(int* __restrict__ counts,
                                                   int* __restrict__ offsets) {
  __shared__ int sums[512];
  const int t = threadIdx.x;
  const int chunk = 40;                       // ceil(20000/512)
  const int lo = t * chunk;
  const int hi = min(lo + chunk, NNODES);
  int s = 0;
  for (int i = lo; i < hi; ++i) s += counts[i];
  sums[t] = s;
  __syncthreads();
  for (int d = 1; d < 512; d <<= 1) {
    const int other = (t >= d) ? sums[t - d] : 0;
    __syncthreads();
    sums[t] += other;
    __syncthreads();
  }
  int run = sums[t] - s;                      // exclusive prefix
  for (int i = lo; i < hi; ++i) {
    offsets[i] = run;
    run += counts[i];
    counts[i] = 0;                            // re-zero: reused as scatter cursor
  }
  if (hi == NNODES) offsets[NNODES] = run;    // == NEDGES
}

// packed[pos] = { j(bits), fc, v0, v1, v2, fc*attrs[0..19], pad[3] }
__global__ __launch_bounds__(256) void pack_scatter_kernel(
    const int* __restrict__ eidx, const float* __restrict__ ew,
    const float* __restrict__ evers, const float* __restrict__ eattr,
    const int* __restrict__ offsets, int* __restrict__ counts,
    float* __restrict__ packed) {
  const int e = blockIdx.x * 256 + threadIdx.x;
  if (e >= NEDGES) return;
  const int i = eidx[e];
  const int j = eidx[NEDGES + e];
  const int pos = offsets[i] + atomicAdd(&counts[i], 1);
  const float w = ew[e];
  const float fc = (w < RCUT_F)
      ? 0.5f * (cosf(PI_F * (1.0f / RCUT_F) * w) + 1.0f) : 0.0f;
  float* p = packed + (size_t)pos * PKF;
  p[0] = __int_as_float(j);
  p[1] = fc;
  p[2] = evers[(size_t)e * 3];
  p[3] = evers[(size_t)e * 3 + 1];
  p[4] = evers[(size_t)e * 3 + 2];
  const float* ae = eattr + (size_t)e * BB;
  #pragma unroll
  for (int b = 0; b < BB; ++b) p[5 + b] = fc * ae[b];
}

// fp16 copy of mu for the gather's random-row reads (halves gather bytes).
__global__ __launch_bounds__(256) void mu2h_kernel(const float* __restrict__ mu,
                                                   __half* __restrict__ muh) {
  const int i = blockIdx.x * 256 + threadIdx.x;        // quad index
  if (i < NNODES * TC / 4) {
    const float4 v = reinterpret_cast<const float4*>(mu)[i];
    __half2* o = reinterpret_cast<__half2*>(muh) + (size_t)i * 2;
    o[0] = __floats2half2_rn(v.x, v.y);
    o[1] = __floats2half2_rn(v.z, v.w);
  }
}

// fallback (no packing) scatter for small ws
__global__ __launch_bounds__(256) void scatter_kernel(const int* __restrict__ eidx,
                                                      const int* __restrict__ offsets,
                                                      int* __restrict__ counts,
                                                      int* __restrict__ edge_list) {
  const int e = blockIdx.x * 256 + threadIdx.x;
  if (e < NEDGES) {
    const int i = eidx[e];
    const int pos = offsets[i] + atomicAdd(&counts[i], 1);
    edge_list[pos] = e;
  }
}

// ---------------------------------------------------------------------------
// Context net: x = silu(q@W1 + b1) @ W2 + b2      [N, 3C]  (stored as fp16)
// ---------------------------------------------------------------------------
#define CNPB 8
__global__ __launch_bounds__(128) void ctx_net_kernel(
    const float* __restrict__ q,
    const float* __restrict__ W1, const float* __restrict__ b1,
    const float* __restrict__ W2, const float* __restrict__ b2,
    __half* __restrict__ x) {
  __shared__ __align__(16) float q_lds[CNPB][CC];
  __shared__ __align__(16) float h_lds[CNPB][CC];
  const int t = threadIdx.x;
  const int node0 = blockIdx.x * CNPB;

  #pragma unroll
  for (int n = 0; n < CNPB; ++n)
    q_lds[n][t] = q[(size_t)(node0 + n) * CC + t];
  __syncthreads();

  float acc[CNPB];
  {
    const float bv = b1[t];
    #pragma unroll
    for (int n = 0; n < CNPB; ++n) acc[n] = bv;
  }
  for (int k = 0; k < CC; k += 8) {
    float w[8];
    #pragma unroll
    for (int r = 0; r < 8; ++r) w[r] = W1[(size_t)(k + r) * CC + t];
    #pragma unroll
    for (int n = 0; n < CNPB; ++n) {
      const float4 q0 = *reinterpret_cast<const float4*>(&q_lds[n][k]);
      const float4 q1 = *reinterpret_cast<const float4*>(&q_lds[n][k + 4]);
      acc[n] = fmaf(q0.x, w[0], acc[n]); acc[n] = fmaf(q0.y, w[1], acc[n]);
      acc[n] = fmaf(q0.z, w[2], acc[n]); acc[n] = fmaf(q0.w, w[3], acc[n]);
      acc[n] = fmaf(q1.x, w[4], acc[n]); acc[n] = fmaf(q1.y, w[5], acc[n]);
      acc[n] = fmaf(q1.z, w[6], acc[n]); acc[n] = fmaf(q1.w, w[7], acc[n]);
    }
  }
  #pragma unroll
  for (int n = 0; n < CNPB; ++n) {
    const float v = acc[n];
    h_lds[n][t] = v / (1.0f + expf(-v));
  }
  __syncthreads();

  float y0[CNPB], y1[CNPB], y2[CNPB];
  {
    const float bb0 = b2[t], bb1 = b2[CC + t], bb2 = b2[2 * CC + t];
    #pragma unroll
    for (int n = 0; n < CNPB; ++n) { y0[n] = bb0; y1[n] = bb1; y2[n] = bb2; }
  }
  for (int k = 0; k < CC; k += 8) {
    float w0[8], w1[8], w2[8];
    #pragma unroll
    for (int r = 0; r < 8; ++r) {
      const size_t row = (size_t)(k + r) * TC;
      w0[r] = W2[row + t];
      w1[r] = W2[row + CC + t];
      w2[r] = W2[row + 2 * CC + t];
    }
    #pragma unroll
    for (int n = 0; n < CNPB; ++n) {
      const float4 h0 = *reinterpret_cast<const float4*>(&h_lds[n][k]);
      const float4 h1 = *reinterpret_cast<const float4*>(&h_lds[n][k + 4]);
      y0[n] = fmaf(h0.x, w0[0], y0[n]); y0[n] = fmaf(h0.y, w0[1], y0[n]);
      y0[n] = fmaf(h0.z, w0[2], y0[n]); y0[n] = fmaf(h0.w, w0[3], y0[n]);
      y0[n] = fmaf(h1.x, w0[4], y0[n]); y0[n] = fmaf(h1.y, w0[5], y0[n]);
      y0[n] = fmaf(h1.z, w0[6], y0[n]); y0[n] = fmaf(h1.w, w0[7], y0[n]);
      y1[n] = fmaf(h0.x, w1[0], y1[n]); y1[n] = fmaf(h0.y, w1[1], y1[n]);
      y1[n] = fmaf(h0.z, w1[2], y1[n]); y1[n] = fmaf(h0.w, w1[3], y1[n]);
      y1[n] = fmaf(h1.x, w1[4], y1[n]); y1[n] = fmaf(h1.y, w1[5], y1[n]);
      y1[n] = fmaf(h1.z, w1[6], y1[n]); y1[n] = fmaf(h1.w, w1[7], y1[n]);
      y2[n] = fmaf(h0.x, w2[0], y2[n]); y2[n] = fmaf(h0.y, w2[1], y2[n]);
      y2[n] = fmaf(h0.z, w2[2], y2[n]); y2[n] = fmaf(h0.w, w2[3], y2[n]);
      y2[n] = fmaf(h1.x, w2[4], y2[n]); y2[n] = fmaf(h1.y, w2[5], y2[n]);
      y2[n] = fmaf(h1.z, w2[6], y2[n]); y2[n] = fmaf(h1.w, w2[7], y2[n]);
    }
  }
  #pragma unroll
  for (int n = 0; n < CNPB; ++n) {
    const size_t base = (size_t)(node0 + n) * TC;
    x[base + t]          = __float2half_rn(y0[n]);
    x[base + CC + t]     = __float2half_rn(y1[n]);
    x[base + 2 * CC + t] = __float2half_rn(y2[n]);
  }
}

// ---------------------------------------------------------------------------
// Gather (packed path), PERSISTENT blocks: grid = 1280 (5 blocks/CU, all
// resident); each block grid-strides over ~16 nodes. Rationale: r5 showed
// OccupancyPercent 57% vs 94% theoretical with 20000 short (~2.3 us) blocks
// -- per-block prologue ramp (wreg fill) + drain was the residency loss.
// wreg/bfc now load once per block, amortized over all its nodes.
//
// Inner edge loop is the r5-verified x2 form, UNCHANGED. History:
//   r3 x2 fp32 = 186 us; r4 manual rotate = 294 us (vmcnt(0) drains);
//   r5 x2 fp16 = 177 us; r6 x4 unroll = 251 us (codegen can't hold 4 chains).
// The x2 body is the codegen sweet spot -- do not touch it.
// ---------------------------------------------------------------------------
#define GTH 384
#define GBLOCKS 1280   // 256 CU x 5 resident blocks (384 thr -> 6 waves, 30/32)

struct EdgeRegs { float4 h0, h1, h2, h3, h4, h5, h6; };

__device__ __forceinline__ EdgeRegs load_edge(const float4* __restrict__ p4,
                                              int k) {
  const float4* p = p4 + (size_t)k * (PKF / 4);
  EdgeRegs E;
  E.h0 = p[0]; E.h1 = p[1]; E.h2 = p[2]; E.h3 = p[3];
  E.h4 = p[4]; E.h5 = p[5]; E.h6 = p[6];
  return E;
}

__device__ __forceinline__ float filter_ws(const EdgeRegs& E,
                                           const float* wreg, float bfc) {
  float ws = E.h0.y * bfc;                    // fc * bf[c]
  ws = fmaf(E.h1.y, wreg[0], ws);  ws = fmaf(E.h1.z, wreg[1], ws);
  ws = fmaf(E.h1.w, wreg[2], ws);  ws = fmaf(E.h2.x, wreg[3], ws);
  ws = fmaf(E.h2.y, wreg[4], ws);  ws = fmaf(E.h2.z, wreg[5], ws);
  ws = fmaf(E.h2.w, wreg[6], ws);  ws = fmaf(E.h3.x, wreg[7], ws);
  ws = fmaf(E.h3.y, wreg[8], ws);  ws = fmaf(E.h3.z, wreg[9], ws);
  ws = fmaf(E.h3.w, wreg[10], ws); ws = fmaf(E.h4.x, wreg[11], ws);
  ws = fmaf(E.h4.y, wreg[12], ws); ws = fmaf(E.h4.z, wreg[13], ws);
  ws = fmaf(E.h4.w, wreg[14], ws); ws = fmaf(E.h5.x, wreg[15], ws);
  ws = fmaf(E.h5.y, wreg[16], ws); ws = fmaf(E.h5.z, wreg[17], ws);
  ws = fmaf(E.h5.w, wreg[18], ws); ws = fmaf(E.h6.x, wreg[19], ws);
  return ws;
}

__global__ __launch_bounds__(GTH) void gather_packed_kernel(
    const float* __restrict__ packed,
    const float* __restrict__ Wf, const float* __restrict__ bf,
    const __half* __restrict__ xh, const __half* __restrict__ muh,
    const float* __restrict__ mu_in,
    const float* __restrict__ q_in, const int* __restrict__ offsets,
    float* __restrict__ qout, float* __restrict__ muout) {
  __shared__ float red[3][CC];
  const int c = threadIdx.x;
  const int grp = c >> 7;          // wave-uniform
  const int ch = c & 127;

  float wreg[BB];
  #pragma unroll
  for (int b = 0; b < BB; ++b) wreg[b] = Wf[b * TC + c];
  const float bfc = bf[c];

  const float4* p4 = reinterpret_cast<const float4*>(packed);

  for (int i = blockIdx.x; i < NNODES; i += GBLOCKS) {
    if (i != (int)blockIdx.x) __syncthreads();   // protect red[] reuse

    const int start = offsets[i];
    const int end = offsets[i + 1];
    float a0 = 0.f, a1 = 0.f, a2 = 0.f;

    int k = start;
    for (; k + 1 < end; k += 2) {
      // issue both packed-row loads up front
      const EdgeRegs A = load_edge(p4, k);
      const EdgeRegs B = load_edge(p4, k + 1);
      const int jA = __float_as_int(A.h0.x);
      const int jB = __float_as_int(B.h0.x);
      // both gathers in flight (fp16 rows)
      const float xA = __half2float(xh[(size_t)jA * TC + c]);
      const float xB = __half2float(xh[(size_t)jB * TC + c]);
      float muA0, muA1, muA2, muB0, muB1, muB2;
      if (grp == 2) {
        const __half* mA = muh + (size_t)jA * TC + ch;
        const __half* mB = muh + (size_t)jB * TC + ch;
        muA0 = __half2float(mA[0]);
        muA1 = __half2float(mA[CC]);
        muA2 = __half2float(mA[2 * CC]);
        muB0 = __half2float(mB[0]);
        muB1 = __half2float(mB[CC]);
        muB2 = __half2float(mB[2 * CC]);
      }
      // filter math overlaps the gathers
      const float wsA = filter_ws(A, wreg, bfc);
      const float wsB = filter_ws(B, wreg, bfc);
      const float xvA = xA * wsA;
      const float xvB = xB * wsB;
      if (grp == 0) {
        a0 += xvA + xvB;
      } else if (grp == 1) {
        a0 = fmaf(xvA, A.h0.z, fmaf(xvB, B.h0.z, a0));
        a1 = fmaf(xvA, A.h0.w, fmaf(xvB, B.h0.w, a1));
        a2 = fmaf(xvA, A.h1.x, fmaf(xvB, B.h1.x, a2));
      } else {
        a0 = fmaf(xvA, muA0, fmaf(xvB, muB0, a0));
        a1 = fmaf(xvA, muA1, fmaf(xvB, muB1, a1));
        a2 = fmaf(xvA, muA2, fmaf(xvB, muB2, a2));
      }
    }
    if (k < end) {
      const EdgeRegs A = load_edge(p4, k);
      const int jA = __float_as_int(A.h0.x);
      const float xA = __half2float(xh[(size_t)jA * TC + c]);
      const float wsA = filter_ws(A, wreg, bfc);
      const float xvA = xA * wsA;
      if (grp == 0) {
        a0 += xvA;
      } else if (grp == 1) {
        a0 = fmaf(xvA, A.h0.z, a0);
        a1 = fmaf(xvA, A.h0.w, a1);
        a2 = fmaf(xvA, A.h1.x, a2);
      } else {
        const __half* mA = muh + (size_t)jA * TC + ch;
        a0 = fmaf(xvA, __half2float(mA[0]), a0);
        a1 = fmaf(xvA, __half2float(mA[CC]), a1);
        a2 = fmaf(xvA, __half2float(mA[2 * CC]), a2);
      }
    }

    if (grp == 1) { red[0][ch] = a0; red[1][ch] = a1; red[2][ch] = a2; }
    __syncthreads();

    if (grp == 0) {
      qout[(size_t)i * CC + ch] = q_in[(size_t)i * CC + ch] + a0;
    } else if (grp == 2) {
      const size_t mb = (size_t)i * TC;
      muout[mb + ch]          = mu_in[mb + ch]          + red[0][ch] + a0;
      muout[mb + CC + ch]     = mu_in[mb + CC + ch]     + red[1][ch] + a1;
      muout[mb + 2 * CC + ch] = mu_in[mb + 2 * CC + ch] + red[2][ch] + a2;
    }
  }
}

// fallback gather (edge_list indirection) for small ws
__global__ __launch_bounds__(GTH) void gather_list_kernel(
    const int* __restrict__ eidx, const float* __restrict__ ew,
    const float* __restrict__ evers, const float* __restrict__ eattr,
    const float* __restrict__ Wf, const float* __restrict__ bf,
    const __half* __restrict__ xh, const float* __restrict__ mu_in,
    const float* __restrict__ q_in,
    const int* __restrict__ offsets, const int* __restrict__ edge_list,
    float* __restrict__ qout, float* __restrict__ muout) {
  __shared__ float red[3][CC];
  const int c = threadIdx.x;
  const int i = blockIdx.x;
  const int grp = c >> 7;
  const int ch = c & 127;
  float wreg[BB];
  #pragma unroll
  for (int b = 0; b < BB; ++b) wreg[b] = Wf[b * TC + c];
  const float bfc = bf[c];
  const int start = offsets[i];
  const int end = offsets[i + 1];
  float a0 = 0.f, a1 = 0.f, a2 = 0.f;
  for (int k = start; k < end; ++k) {
    const int e = edge_list[k];
    const int j = eidx[NEDGES + e];
    const float w = ew[e];
    const float fc = (w < RCUT_F)
        ? 0.5f * (cosf(PI_F * (1.0f / RCUT_F) * w) + 1.0f) : 0.0f;
    const float2* ae2 = reinterpret_cast<const float2*>(eattr + (size_t)e * BB);
    float wsum = bfc;
    #pragma unroll
    for (int b = 0; b < BB / 2; ++b) {
      const float2 a = ae2[b];
      wsum = fmaf(a.x, wreg[2 * b], wsum);
      wsum = fmaf(a.y, wreg[2 * b + 1], wsum);
    }
    wsum *= fc;
    const float xv = __half2float(xh[(size_t)j * TC + c]) * wsum;
    if (grp == 0) {
      a0 += xv;
    } else if (grp == 1) {
      const float v0 = evers[(size_t)e * 3];
      const float v1 = evers[(size_t)e * 3 + 1];
      const float v2 = evers[(size_t)e * 3 + 2];
      a0 = fmaf(xv, v0, a0); a1 = fmaf(xv, v1, a1); a2 = fmaf(xv, v2, a2);
    } else {
      const float* muj = mu_in + (size_t)j * TC + ch;
      a0 = fmaf(xv, muj[0], a0);
      a1 = fmaf(xv, muj[CC], a1);
      a2 = fmaf(xv, muj[2 * CC], a2);
    }
  }
  if (grp == 1) { red[0][ch] = a0; red[1][ch] = a1; red[2][ch] = a2; }
  __syncthreads();
  if (grp == 0) {
    qout[(size_t)i * CC + ch] = q_in[(size_t)i * CC + ch] + a0;
  } else if (grp == 2) {
    const size_t mb = (size_t)i * TC;
    muout[mb + ch]          = mu_in[mb + ch]          + red[0][ch] + a0;
    muout[mb + CC + ch]     = mu_in[mb + CC + ch]     + red[1][ch] + a1;
    muout[mb + 2 * CC + ch] = mu_in[mb + 2 * CC + ch] + red[2][ch] + a2;
  }
}

// ---------------------------------------------------------------------------
// Mixing kernel v4 (verified r3/r5): LDS-staged mu, 20 KB LDS, no spill.
// VGPR-allocator model (verified r0-r3): cap = f(LDS-implied occupancy).
// 20KB -> 8 blk/CU = 4 waves/SIMD -> cap 128 >= ~90 needed => no spill.
// ---------------------------------------------------------------------------
#define MNPB 8
__global__ __launch_bounds__(128) void mix_kernel(
    const float* __restrict__ Wmix, const float* __restrict__ Wm1,
    const float* __restrict__ bm1, const float* __restrict__ Wm2,
    const float* __restrict__ bm2, float* __restrict__ qout,
    float* __restrict__ muout) {
  __shared__ __align__(16) float mu_lds[MNPB][3][CC];   // 12 KB
  __shared__ __align__(16) float vn_lds[MNPB][CC];      // 4 KB
  __shared__ __align__(16) float h2_lds[MNPB][CC];      // 4 KB

  const int t = threadIdx.x;
  const int node0 = blockIdx.x * MNPB;

  #pragma unroll
  for (int n = 0; n < MNPB; ++n) {
    const size_t mb = (size_t)(node0 + n) * TC;
    mu_lds[n][0][t] = muout[mb + t];
    mu_lds[n][1][t] = muout[mb + CC + t];
    mu_lds[n][2][t] = muout[mb + 2 * CC + t];
  }
  __syncthreads();

  // ---- phase 1: mu_mix from LDS-staged mu ----
  float mW[MNPB][3], sdot[MNPB];
  {
    float mV[MNPB][3];
    #pragma unroll
    for (int n = 0; n < MNPB; ++n)
      #pragma unroll
      for (int v = 0; v < 3; ++v) { mV[n][v] = 0.0f; mW[n][v] = 0.0f; }

    for (int c = 0; c < CC; c += 8) {
      float wv[8], ww[8];
      #pragma unroll
      for (int r = 0; r < 8; ++r) {
        const size_t row = (size_t)(c + r) * (2 * CC);
        wv[r] = Wmix[row + t];
        ww[r] = Wmix[row + CC + t];
      }
      #pragma unroll
      for (int n = 0; n < MNPB; ++n) {
        #pragma unroll
        for (int v = 0; v < 3; ++v) {
          const float4 m0 = *reinterpret_cast<const float4*>(&mu_lds[n][v][c]);
          const float4 m1 = *reinterpret_cast<const float4*>(&mu_lds[n][v][c + 4]);
          float a = mV[n][v], b = mW[n][v];
          a = fmaf(m0.x, wv[0], a); a = fmaf(m0.y, wv[1], a);
          a = fmaf(m0.z, wv[2], a); a = fmaf(m0.w, wv[3], a);
          a = fmaf(m1.x, wv[4], a); a = fmaf(m1.y, wv[5], a);
          a = fmaf(m1.z, wv[6], a); a = fmaf(m1.w, wv[7], a);
          b = fmaf(m0.x, ww[0], b); b = fmaf(m0.y, ww[1], b);
          b = fmaf(m0.z, ww[2], b); b = fmaf(m0.w, ww[3], b);
          b = fmaf(m1.x, ww[4], b); b = fmaf(m1.y, ww[5], b);
          b = fmaf(m1.z, ww[6], b); b = fmaf(m1.w, ww[7], b);
          mV[n][v] = a; mW[n][v] = b;
        }
      }
    }
    #pragma unroll
    for (int n = 0; n < MNPB; ++n) {
      const float ss = mV[n][0] * mV[n][0] + mV[n][1] * mV[n][1] + mV[n][2] * mV[n][2];
      vn_lds[n][t] = sqrtf(ss + 1e-8f);
      sdot[n] = mV[n][0] * mW[n][0] + mV[n][1] * mW[n][1] + mV[n][2] * mW[n][2];
    }
  } // mV dies here
  __syncthreads();   // vn_lds visible

  // ---- phase 2: silu(ctx @ Wm1 + bm1) ----
  float acc[MNPB];
  {
    const float bv = bm1[t];
    #pragma unroll
    for (int n = 0; n < MNPB; ++n) acc[n] = bv;
  }
  // ctx first half: q, wave-uniform broadcast from global (L3-hot)
  for (int k = 0; k < CC; k += 8) {
    float w[8];
    #pragma unroll
    for (int r = 0; r < 8; ++r) w[r] = Wm1[(size_t)(k + r) * CC + t];
    #pragma unroll
    for (int n = 0; n < MNPB; ++n) {
      const float* qrow = qout + (size_t)(node0 + n) * CC + k;
      const float4 c0 = *reinterpret_cast<const float4*>(qrow);
      const float4 c1 = *reinterpret_cast<const float4*>(qrow + 4);
      acc[n] = fmaf(c0.x, w[0], acc[n]); acc[n] = fmaf(c0.y, w[1], acc[n]);
      acc[n] = fmaf(c0.z, w[2], acc[n]); acc[n] = fmaf(c0.w, w[3], acc[n]);
      acc[n] = fmaf(c1.x, w[4], acc[n]); acc[n] = fmaf(c1.y, w[5], acc[n]);
      acc[n] = fmaf(c1.z, w[6], acc[n]); acc[n] = fmaf(c1.w, w[7], acc[n]);
    }
  }
  // ctx second half: mu_Vn from LDS (broadcast)
  for (int k = 0; k < CC; k += 8) {
    float w[8];
    #pragma unroll
    for (int r = 0; r < 8; ++r) w[r] = Wm1[(size_t)(CC + k + r) * CC + t];
    #pragma unroll
    for (int n = 0; n < MNPB; ++n) {
      const float4 c0 = *reinterpret_cast<const float4*>(&vn_lds[n][k]);
      const float4 c1 = *reinterpret_cast<const float4*>(&vn_lds[n][k + 4]);
      acc[n] = fmaf(c0.x, w[0], acc[n]); acc[n] = fmaf(c0.y, w[1], acc[n]);
      acc[n] = fmaf(c0.z, w[2], acc[n]); acc[n] = fmaf(c0.w, w[3], acc[n]);
      acc[n] = fmaf(c1.x, w[4], acc[n]); acc[n] = fmaf(c1.y, w[5], acc[n]);
      acc[n] = fmaf(c1.z, w[6], acc[n]); acc[n] = fmaf(c1.w, w[7], acc[n]);
    }
  }
  #pragma unroll
  for (int n = 0; n < MNPB; ++n) {
    const float v = acc[n];
    h2_lds[n][t] = v / (1.0f + expf(-v));
  }
  __syncthreads();   // h2 visible; all phase-2 broadcast reads of qout done

  // ---- phase 3: y = h2 @ Wm2 + bm2 ----
  float y0[MNPB], y1[MNPB], y2[MNPB];
  {
    const float bb0 = bm2[t], bb1 = bm2[CC + t], bb2 = bm2[2 * CC + t];
    #pragma unroll
    for (int n = 0; n < MNPB; ++n) { y0[n] = bb0; y1[n] = bb1; y2[n] = bb2; }
  }
  for (int k = 0; k < CC; k += 8) {
    float w0[8], w1[8], w2[8];
    #pragma unroll
    for (int r = 0; r < 8; ++r) {
      const size_t row = (size_t)(k + r) * TC;
      w0[r] = Wm2[row + t];
      w1[r] = Wm2[row + CC + t];
      w2[r] = Wm2[row + 2 * CC + t];
    }
    #pragma unroll
    for (int n = 0; n < MNPB; ++n) {
      const float4 h0 = *reinterpret_cast<const float4*>(&h2_lds[n][k]);
      const float4 h1 = *reinterpret_cast<const float4*>(&h2_lds[n][k + 4]);
      y0[n] = fmaf(h0.x, w0[0], y0[n]); y0[n] = fmaf(h0.y, w0[1], y0[n]);
      y0[n] = fmaf(h0.z, w0[2], y0[n]); y0[n] = fmaf(h0.w, w0[3], y0[n]);
      y0[n] = fmaf(h1.x, w0[4], y0[n]); y0[n] = fmaf(h1.y, w0[5], y0[n]);
      y0[n] = fmaf(h1.z, w0[6], y0[n]); y0[n] = fmaf(h1.w, w0[7], y0[n]);
      y1[n] = fmaf(h0.x, w1[0], y1[n]); y1[n] = fmaf(h0.y, w1[1], y1[n]);
      y1[n] = fmaf(h0.z, w1[2], y1[n]); y1[n] = fmaf(h0.w, w1[3], y1[n]);
      y1[n] = fmaf(h1.x, w1[4], y1[n]); y1[n] = fmaf(h1.y, w1[5], y1[n]);
      y1[n] = fmaf(h1.z, w1[6], y1[n]); y1[n] = fmaf(h1.w, w1[7], y1[n]);
      y2[n] = fmaf(h0.x, w2[0], y2[n]); y2[n] = fmaf(h0.y, w2[1], y2[n]);
      y2[n] = fmaf(h0.z, w2[2], y2[n]); y2[n] = fmaf(h0.w, w2[3], y2[n]);
      y2[n] = fmaf(h1.x, w2[4], y2[n]); y2[n] = fmaf(h1.y, w2[5], y2[n]);
      y2[n] = fmaf(h1.z, w2[6], y2[n]); y2[n] = fmaf(h1.w, w2[7], y2[n]);
    }
  }

  // ---- epilogue: q re-read coalesced (L3-hot), mu residual from LDS ----
  #pragma unroll
  for (int n = 0; n < MNPB; ++n) {
    const size_t qb = (size_t)(node0 + n) * CC;
    qout[qb + t] = qout[qb + t] + y0[n] + y2[n] * sdot[n];
    const size_t mb = (size_t)(node0 + n) * TC;
    muout[mb + t]          = mu_lds[n][0][t] + y1[n] * mW[n][0];
    muout[mb + CC + t]     = mu_lds[n][1][t] + y1[n] * mW[n][1];
    muout[mb + 2 * CC + t] = mu_lds[n][2][t] + y1[n] * mW[n][2];
  }
}

// ---------------------------------------------------------------------------
extern "C" void kernel_launch(void* const* d_in, const int* in_sizes, int n_in,
                              void* d_out, int out_size, void* d_ws, size_t ws_size,
                              hipStream_t stream) {
  const float* q     = (const float*)d_in[0];
  const float* mu    = (const float*)d_in[1];
  const int*   eidx  = (const int*)d_in[2];
  const float* ew    = (const float*)d_in[3];
  const float* evers = (const float*)d_in[4];
  const float* eattr = (const float*)d_in[5];
  const float* Wf    = (const float*)d_in[6];
  const float* bf    = (const float*)d_in[7];
  const float* W1    = (const float*)d_in[8];
  const float* b1    = (const float*)d_in[9];
  const float* W2    = (const float*)d_in[10];
  const float* b2    = (const float*)d_in[11];
  const float* Wmix  = (const float*)d_in[12];
  const float* Wm1   = (const float*)d_in[13];
  const float* bm1   = (const float*)d_in[14];
  const float* Wm2   = (const float*)d_in[15];
  const float* bm2   = (const float*)d_in[16];

  float* out   = (float*)d_out;
  float* qout  = out;                                // [N, C]
  float* muout = out + (size_t)NNODES * CC;          // [N, 3, C]

  // workspace layout: packed | xh (fp16) | muh (fp16) | counts | offsets
  float*  packed  = (float*)d_ws;                           // [E*28] floats
  __half* xh      = (__half*)(packed + (size_t)NEDGES * PKF);   // [N*3C] halves
  __half* muh     = xh + (size_t)NNODES * TC;                   // [N*3C] halves
  int*    counts  = (int*)(muh + (size_t)NNODES * TC);      // [N]
  int*    offsets = counts + NNODES;                        // [N+1]
  const size_t need_packed =
      (size_t)NEDGES * PKF * 4 + (size_t)NNODES * TC * 2 * 2 +
      (2 * NNODES + 2) * 4 + 256;
  const bool use_packed = ws_size >= need_packed;

  if (use_packed) {
    zero_counts_kernel<<<(NNODES + 255) / 256, 256, 0, stream>>>(counts);
    hist_kernel<<<(NEDGES + 255) / 256, 256, 0, stream>>>(eidx, counts);
    scan_kernel<<<1, 512, 0, stream>>>(counts, offsets);
    pack_scatter_kernel<<<(NEDGES + 255) / 256, 256, 0, stream>>>(
        eidx, ew, evers, eattr, offsets, counts, packed);
    mu2h_kernel<<<(NNODES * TC / 4 + 255) / 256, 256, 0, stream>>>(mu, muh);
    ctx_net_kernel<<<NNODES / CNPB, 128, 0, stream>>>(q, W1, b1, W2, b2, xh);
    gather_packed_kernel<<<GBLOCKS, GTH, 0, stream>>>(
        packed, Wf, bf, xh, muh, mu, q, offsets, qout, muout);
  } else {
    // fallback layout (xh fp16 | counts | offsets | edge_list)
    __half* xf       = (__half*)d_ws;
    int*   countsf   = (int*)(xf + (size_t)NNODES * TC);
    int*   offsetsf  = countsf + NNODES;
    int*   edge_list = offsetsf + NNODES + 1;
    zero_counts_kernel<<<(NNODES + 255) / 256, 256, 0, stream>>>(countsf);
    hist_kernel<<<(NEDGES + 255) / 256, 256, 0, stream>>>(eidx, countsf);
    scan_kernel<<<1, 512, 0, stream>>>(countsf, offsetsf);
    scatter_kernel<<<(NEDGES + 255) / 256, 256, 0, stream>>>(eidx, offsetsf,
                                                             countsf, edge_list);
    ctx_net_kernel<<<NNODES / CNPB, 128, 0, stream>>>(q, W1, b1, W2, b2, xf);
    gather_list_kernel<<<NNODES, GTH, 0, stream>>>(eidx, ew, evers, eattr,
                                                   Wf, bf, xf, mu, q,
                                                   offsetsf, edge_list,
                                                   qout, muout);
  }
  mix_kernel<<<NNODES / MNPB, 128, 0, stream>>>(Wmix, Wm1, bm1, Wm2, bm2,
                                                qout, muout);
}

// Round 8
// 624.741 us; speedup vs baseline: 1.0589x; 1.0535x over previous
//
#include <hip/hip_runtime.h>
#include <hip/hip_fp16.h>
#include <math.h>

#define NNODES 20000
#define NEDGES 320000
#define CC 128          // channels
#define TC 384          // 3*C
#define BB 20           // basis dim
#define RCUT_F 5.0f
#define PI_F 3.14159265358979323846f
#define PKF 28          // packed floats per edge (112 B, float4-aligned)

// ---------------------------------------------------------------------------
// CSR build: zero -> histogram -> single-block scan -> pack+scatter
// ---------------------------------------------------------------------------
__global__ __launch_bounds__(256) void zero_counts_kernel(int* __restrict__ counts) {
  const int i = blockIdx.x * 256 + threadIdx.x;
  if (i < NNODES) counts[i] = 0;
}

__global__ __launch_bounds__(256) void hist_kernel(const int* __restrict__ eidx,
                                                   int* __restrict__ counts) {
  const int e = blockIdx.x * 256 + threadIdx.x;
  if (e < NEDGES) atomicAdd(&counts[eidx[e]], 1);
}

__global__ __launch_bounds__(512) void scan_kernel(int* __restrict__ counts,
                                                   int* __restrict__ offsets) {
  __shared__ int sums[512];
  const int t = threadIdx.x;
  const int chunk = 40;                       // ceil(20000/512)
  const int lo = t * chunk;
  const int hi = min(lo + chunk, NNODES);
  int s = 0;
  for (int i = lo; i < hi; ++i) s += counts[i];
  sums[t] = s;
  __syncthreads();
  for (int d = 1; d < 512; d <<= 1) {
    const int other = (t >= d) ? sums[t - d] : 0;
    __syncthreads();
    sums[t] += other;
    __syncthreads();
  }
  int run = sums[t] - s;                      // exclusive prefix
  for (int i = lo; i < hi; ++i) {
    offsets[i] = run;
    run += counts[i];
    counts[i] = 0;                            // re-zero: reused as scatter cursor
  }
  if (hi == NNODES) offsets[NNODES] = run;    // == NEDGES
}

// packed[pos] = { j(bits), fc, v0, v1, v2, fc*attrs[0..19], pad[3] }
__global__ __launch_bounds__(256) void pack_scatter_kernel(
    const int* __restrict__ eidx, const float* __restrict__ ew,
    const float* __restrict__ evers, const float* __restrict__ eattr,
    const int* __restrict__ offsets, int* __restrict__ counts,
    float* __restrict__ packed) {
  const int e = blockIdx.x * 256 + threadIdx.x;
  if (e >= NEDGES) return;
  const int i = eidx[e];
  const int j = eidx[NEDGES + e];
  const int pos = offsets[i] + atomicAdd(&counts[i], 1);
  const float w = ew[e];
  const float fc = (w < RCUT_F)
      ? 0.5f * (cosf(PI_F * (1.0f / RCUT_F) * w) + 1.0f) : 0.0f;
  float* p = packed + (size_t)pos * PKF;
  p[0] = __int_as_float(j);
  p[1] = fc;
  p[2] = evers[(size_t)e * 3];
  p[3] = evers[(size_t)e * 3 + 1];
  p[4] = evers[(size_t)e * 3 + 2];
  const float* ae = eattr + (size_t)e * BB;
  #pragma unroll
  for (int b = 0; b < BB; ++b) p[5 + b] = fc * ae[b];
}

// fp16 INTERLEAVED copy of mu: muh4[n*CC + c] = {mu_x, mu_y, mu_z, 0} as 4
// halves in one 8-byte word. r7 analysis: grp2 was the straggler wave-group
// (4 loads + 4 addr-calcs per edge vs 1 for grp0/1); interleaving makes the
// per-edge mu access ONE aligned 8B load. Costs 1024 vs 768 B/edge (pad).
__global__ __launch_bounds__(256) void mu2h4_kernel(const float* __restrict__ mu,
                                                    float2* __restrict__ muh4) {
  const int idx = blockIdx.x * 256 + threadIdx.x;      // node*CC + ch
  if (idx < NNODES * CC) {
    const int n = idx / CC;
    const int ch = idx & (CC - 1);
    const float* m = mu + (size_t)n * TC + ch;
    const __half2 lo = __floats2half2_rn(m[0], m[CC]);
    const __half2 hi = __floats2half2_rn(m[2 * CC], 0.0f);
    float2 o;
    o.x = __uint_as_float(*reinterpret_cast<const unsigned int*>(&lo));
    o.y = __uint_as_float(*reinterpret_cast<const unsigned int*>(&hi));
    muh4[idx] = o;
  }
}

// fallback (no packing) scatter for small ws
__global__ __launch_bounds__(256) void scatter_kernel(const int* __restrict__ eidx,
                                                      const int* __restrict__ offsets,
                                                      int* __restrict__ counts,
                                                      int* __restrict__ edge_list) {
  const int e = blockIdx.x * 256 + threadIdx.x;
  if (e < NEDGES) {
    const int i = eidx[e];
    const int pos = offsets[i] + atomicAdd(&counts[i], 1);
    edge_list[pos] = e;
  }
}

// ---------------------------------------------------------------------------
// Context net: x = silu(q@W1 + b1) @ W2 + b2      [N, 3C]  (stored as fp16)
// ---------------------------------------------------------------------------
#define CNPB 8
__global__ __launch_bounds__(128) void ctx_net_kernel(
    const float* __restrict__ q,
    const float* __restrict__ W1, const float* __restrict__ b1,
    const float* __restrict__ W2, const float* __restrict__ b2,
    __half* __restrict__ x) {
  __shared__ __align__(16) float q_lds[CNPB][CC];
  __shared__ __align__(16) float h_lds[CNPB][CC];
  const int t = threadIdx.x;
  const int node0 = blockIdx.x * CNPB;

  #pragma unroll
  for (int n = 0; n < CNPB; ++n)
    q_lds[n][t] = q[(size_t)(node0 + n) * CC + t];
  __syncthreads();

  float acc[CNPB];
  {
    const float bv = b1[t];
    #pragma unroll
    for (int n = 0; n < CNPB; ++n) acc[n] = bv;
  }
  for (int k = 0; k < CC; k += 8) {
    float w[8];
    #pragma unroll
    for (int r = 0; r < 8; ++r) w[r] = W1[(size_t)(k + r) * CC + t];
    #pragma unroll
    for (int n = 0; n < CNPB; ++n) {
      const float4 q0 = *reinterpret_cast<const float4*>(&q_lds[n][k]);
      const float4 q1 = *reinterpret_cast<const float4*>(&q_lds[n][k + 4]);
      acc[n] = fmaf(q0.x, w[0], acc[n]); acc[n] = fmaf(q0.y, w[1], acc[n]);
      acc[n] = fmaf(q0.z, w[2], acc[n]); acc[n] = fmaf(q0.w, w[3], acc[n]);
      acc[n] = fmaf(q1.x, w[4], acc[n]); acc[n] = fmaf(q1.y, w[5], acc[n]);
      acc[n] = fmaf(q1.z, w[6], acc[n]); acc[n] = fmaf(q1.w, w[7], acc[n]);
    }
  }
  #pragma unroll
  for (int n = 0; n < CNPB; ++n) {
    const float v = acc[n];
    h_lds[n][t] = v / (1.0f + expf(-v));
  }
  __syncthreads();

  float y0[CNPB], y1[CNPB], y2[CNPB];
  {
    const float bb0 = b2[t], bb1 = b2[CC + t], bb2 = b2[2 * CC + t];
    #pragma unroll
    for (int n = 0; n < CNPB; ++n) { y0[n] = bb0; y1[n] = bb1; y2[n] = bb2; }
  }
  for (int k = 0; k < CC; k += 8) {
    float w0[8], w1[8], w2[8];
    #pragma unroll
    for (int r = 0; r < 8; ++r) {
      const size_t row = (size_t)(k + r) * TC;
      w0[r] = W2[row + t];
      w1[r] = W2[row + CC + t];
      w2[r] = W2[row + 2 * CC + t];
    }
    #pragma unroll
    for (int n = 0; n < CNPB; ++n) {
      const float4 h0 = *reinterpret_cast<const float4*>(&h_lds[n][k]);
      const float4 h1 = *reinterpret_cast<const float4*>(&h_lds[n][k + 4]);
      y0[n] = fmaf(h0.x, w0[0], y0[n]); y0[n] = fmaf(h0.y, w0[1], y0[n]);
      y0[n] = fmaf(h0.z, w0[2], y0[n]); y0[n] = fmaf(h0.w, w0[3], y0[n]);
      y0[n] = fmaf(h1.x, w0[4], y0[n]); y0[n] = fmaf(h1.y, w0[5], y0[n]);
      y0[n] = fmaf(h1.z, w0[6], y0[n]); y0[n] = fmaf(h1.w, w0[7], y0[n]);
      y1[n] = fmaf(h0.x, w1[0], y1[n]); y1[n] = fmaf(h0.y, w1[1], y1[n]);
      y1[n] = fmaf(h0.z, w1[2], y1[n]); y1[n] = fmaf(h0.w, w1[3], y1[n]);
      y1[n] = fmaf(h1.x, w1[4], y1[n]); y1[n] = fmaf(h1.y, w1[5], y1[n]);
      y1[n] = fmaf(h1.z, w1[6], y1[n]); y1[n] = fmaf(h1.w, w1[7], y1[n]);
      y2[n] = fmaf(h0.x, w2[0], y2[n]); y2[n] = fmaf(h0.y, w2[1], y2[n]);
      y2[n] = fmaf(h0.z, w2[2], y2[n]); y2[n] = fmaf(h0.w, w2[3], y2[n]);
      y2[n] = fmaf(h1.x, w2[4], y2[n]); y2[n] = fmaf(h1.y, w2[5], y2[n]);
      y2[n] = fmaf(h1.z, w2[6], y2[n]); y2[n] = fmaf(h1.w, w2[7], y2[n]);
    }
  }
  #pragma unroll
  for (int n = 0; n < CNPB; ++n) {
    const size_t base = (size_t)(node0 + n) * TC;
    x[base + t]          = __float2half_rn(y0[n]);
    x[base + CC + t]     = __float2half_rn(y1[n]);
    x[base + 2 * CC + t] = __float2half_rn(y2[n]);
  }
}

// ---------------------------------------------------------------------------
// Gather (packed path): one block of 384 threads per node; thread c owns
// filter column c (weights in 20 regs). Inner loop = r5-verified x2 form.
// Scheduling-level history (all A/B'd against this structure):
//   r3 x2 fp32 = 186 us | r4 manual rotate = 294 (vmcnt(0) drains)
//   r5 x2 fp16 = 177    | r6 x4 unroll = 251 (codegen can't hold 4 chains)
//   r7 persistent-1280  = 237 (per-node barrier + no block oversubscription)
// => 20000 short blocks + x2 body is the scheduling optimum; don't touch.
// r8 change: mu gathered from INTERLEAVED muh4 (one 8B load vs 3 strided
// half loads) -- grp2 was the straggler wave-group (4 loads/edge vs 1).
// ---------------------------------------------------------------------------
#define GTH 384

struct EdgeRegs { float4 h0, h1, h2, h3, h4, h5, h6; };

__device__ __forceinline__ EdgeRegs load_edge(const float4* __restrict__ p4,
                                              int k) {
  const float4* p = p4 + (size_t)k * (PKF / 4);
  EdgeRegs E;
  E.h0 = p[0]; E.h1 = p[1]; E.h2 = p[2]; E.h3 = p[3];
  E.h4 = p[4]; E.h5 = p[5]; E.h6 = p[6];
  return E;
}

__device__ __forceinline__ float filter_ws(const EdgeRegs& E,
                                           const float* wreg, float bfc) {
  float ws = E.h0.y * bfc;                    // fc * bf[c]
  ws = fmaf(E.h1.y, wreg[0], ws);  ws = fmaf(E.h1.z, wreg[1], ws);
  ws = fmaf(E.h1.w, wreg[2], ws);  ws = fmaf(E.h2.x, wreg[3], ws);
  ws = fmaf(E.h2.y, wreg[4], ws);  ws = fmaf(E.h2.z, wreg[5], ws);
  ws = fmaf(E.h2.w, wreg[6], ws);  ws = fmaf(E.h3.x, wreg[7], ws);
  ws = fmaf(E.h3.y, wreg[8], ws);  ws = fmaf(E.h3.z, wreg[9], ws);
  ws = fmaf(E.h3.w, wreg[10], ws); ws = fmaf(E.h4.x, wreg[11], ws);
  ws = fmaf(E.h4.y, wreg[12], ws); ws = fmaf(E.h4.z, wreg[13], ws);
  ws = fmaf(E.h4.w, wreg[14], ws); ws = fmaf(E.h5.x, wreg[15], ws);
  ws = fmaf(E.h5.y, wreg[16], ws); ws = fmaf(E.h5.z, wreg[17], ws);
  ws = fmaf(E.h5.w, wreg[18], ws); ws = fmaf(E.h6.x, wreg[19], ws);
  return ws;
}

__device__ __forceinline__ void unpack_mu4(const float2 m, float& m0,
                                           float& m1, float& m2) {
  const unsigned int ulo = __float_as_uint(m.x);
  const unsigned int uhi = __float_as_uint(m.y);
  const __half2 lo = *reinterpret_cast<const __half2*>(&ulo);
  const __half2 hi = *reinterpret_cast<const __half2*>(&uhi);
  m0 = __half2float(lo.x);
  m1 = __half2float(lo.y);
  m2 = __half2float(hi.x);
}

__global__ __launch_bounds__(GTH) void gather_packed_kernel(
    const float* __restrict__ packed,
    const float* __restrict__ Wf, const float* __restrict__ bf,
    const __half* __restrict__ xh, const float2* __restrict__ muh4,
    const float* __restrict__ mu_in,
    const float* __restrict__ q_in, const int* __restrict__ offsets,
    float* __restrict__ qout, float* __restrict__ muout) {
  __shared__ float red[3][CC];
  const int c = threadIdx.x;
  const int i = blockIdx.x;
  const int grp = c >> 7;          // wave-uniform
  const int ch = c & 127;

  float wreg[BB];
  #pragma unroll
  for (int b = 0; b < BB; ++b) wreg[b] = Wf[b * TC + c];
  const float bfc = bf[c];

  const float4* p4 = reinterpret_cast<const float4*>(packed);
  const int start = offsets[i];
  const int end = offsets[i + 1];
  float a0 = 0.f, a1 = 0.f, a2 = 0.f;

  int k = start;
  for (; k + 1 < end; k += 2) {
    // issue both packed-row loads up front
    const EdgeRegs A = load_edge(p4, k);
    const EdgeRegs B = load_edge(p4, k + 1);
    const int jA = __float_as_int(A.h0.x);
    const int jB = __float_as_int(B.h0.x);
    // both gathers in flight (fp16 rows)
    const float xA = __half2float(xh[(size_t)jA * TC + c]);
    const float xB = __half2float(xh[(size_t)jB * TC + c]);
    float muA0, muA1, muA2, muB0, muB1, muB2;
    if (grp == 2) {
      const float2 mA = muh4[(size_t)jA * CC + ch];
      const float2 mB = muh4[(size_t)jB * CC + ch];
      unpack_mu4(mA, muA0, muA1, muA2);
      unpack_mu4(mB, muB0, muB1, muB2);
    }
    // filter math overlaps the gathers
    const float wsA = filter_ws(A, wreg, bfc);
    const float wsB = filter_ws(B, wreg, bfc);
    const float xvA = xA * wsA;
    const float xvB = xB * wsB;
    if (grp == 0) {
      a0 += xvA + xvB;
    } else if (grp == 1) {
      a0 = fmaf(xvA, A.h0.z, fmaf(xvB, B.h0.z, a0));
      a1 = fmaf(xvA, A.h0.w, fmaf(xvB, B.h0.w, a1));
      a2 = fmaf(xvA, A.h1.x, fmaf(xvB, B.h1.x, a2));
    } else {
      a0 = fmaf(xvA, muA0, fmaf(xvB, muB0, a0));
      a1 = fmaf(xvA, muA1, fmaf(xvB, muB1, a1));
      a2 = fmaf(xvA, muA2, fmaf(xvB, muB2, a2));
    }
  }
  if (k < end) {
    const EdgeRegs A = load_edge(p4, k);
    const int jA = __float_as_int(A.h0.x);
    const float xA = __half2float(xh[(size_t)jA * TC + c]);
    const float wsA = filter_ws(A, wreg, bfc);
    const float xvA = xA * wsA;
    if (grp == 0) {
      a0 += xvA;
    } else if (grp == 1) {
      a0 = fmaf(xvA, A.h0.z, a0);
      a1 = fmaf(xvA, A.h0.w, a1);
      a2 = fmaf(xvA, A.h1.x, a2);
    } else {
      float muA0, muA1, muA2;
      const float2 mA = muh4[(size_t)jA * CC + ch];
      unpack_mu4(mA, muA0, muA1, muA2);
      a0 = fmaf(xvA, muA0, a0);
      a1 = fmaf(xvA, muA1, a1);
      a2 = fmaf(xvA, muA2, a2);
    }
  }

  if (grp == 1) { red[0][ch] = a0; red[1][ch] = a1; red[2][ch] = a2; }
  __syncthreads();

  if (grp == 0) {
    qout[(size_t)i * CC + ch] = q_in[(size_t)i * CC + ch] + a0;
  } else if (grp == 2) {
    const size_t mb = (size_t)i * TC;
    muout[mb + ch]          = mu_in[mb + ch]          + red[0][ch] + a0;
    muout[mb + CC + ch]     = mu_in[mb + CC + ch]     + red[1][ch] + a1;
    muout[mb + 2 * CC + ch] = mu_in[mb + 2 * CC + ch] + red[2][ch] + a2;
  }
}

// fallback gather (edge_list indirection) for small ws
__global__ __launch_bounds__(GTH) void gather_list_kernel(
    const int* __restrict__ eidx, const float* __restrict__ ew,
    const float* __restrict__ evers, const float* __restrict__ eattr,
    const float* __restrict__ Wf, const float* __restrict__ bf,
    const __half* __restrict__ xh, const float* __restrict__ mu_in,
    const float* __restrict__ q_in,
    const int* __restrict__ offsets, const int* __restrict__ edge_list,
    float* __restrict__ qout, float* __restrict__ muout) {
  __shared__ float red[3][CC];
  const int c = threadIdx.x;
  const int i = blockIdx.x;
  const int grp = c >> 7;
  const int ch = c & 127;
  float wreg[BB];
  #pragma unroll
  for (int b = 0; b < BB; ++b) wreg[b] = Wf[b * TC + c];
  const float bfc = bf[c];
  const int start = offsets[i];
  const int end = offsets[i + 1];
  float a0 = 0.f, a1 = 0.f, a2 = 0.f;
  for (int k = start; k < end; ++k) {
    const int e = edge_list[k];
    const int j = eidx[NEDGES + e];
    const float w = ew[e];
    const float fc = (w < RCUT_F)
        ? 0.5f * (cosf(PI_F * (1.0f / RCUT_F) * w) + 1.0f) : 0.0f;
    const float2* ae2 = reinterpret_cast<const float2*>(eattr + (size_t)e * BB);
    float wsum = bfc;
    #pragma unroll
    for (int b = 0; b < BB / 2; ++b) {
      const float2 a = ae2[b];
      wsum = fmaf(a.x, wreg[2 * b], wsum);
      wsum = fmaf(a.y, wreg[2 * b + 1], wsum);
    }
    wsum *= fc;
    const float xv = __half2float(xh[(size_t)j * TC + c]) * wsum;
    if (grp == 0) {
      a0 += xv;
    } else if (grp == 1) {
      const float v0 = evers[(size_t)e * 3];
      const float v1 = evers[(size_t)e * 3 + 1];
      const float v2 = evers[(size_t)e * 3 + 2];
      a0 = fmaf(xv, v0, a0); a1 = fmaf(xv, v1, a1); a2 = fmaf(xv, v2, a2);
    } else {
      const float* muj = mu_in + (size_t)j * TC + ch;
      a0 = fmaf(xv, muj[0], a0);
      a1 = fmaf(xv, muj[CC], a1);
      a2 = fmaf(xv, muj[2 * CC], a2);
    }
  }
  if (grp == 1) { red[0][ch] = a0; red[1][ch] = a1; red[2][ch] = a2; }
  __syncthreads();
  if (grp == 0) {
    qout[(size_t)i * CC + ch] = q_in[(size_t)i * CC + ch] + a0;
  } else if (grp == 2) {
    const size_t mb = (size_t)i * TC;
    muout[mb + ch]          = mu_in[mb + ch]          + red[0][ch] + a0;
    muout[mb + CC + ch]     = mu_in[mb + CC + ch]     + red[1][ch] + a1;
    muout[mb + 2 * CC + ch] = mu_in[mb + 2 * CC + ch] + red[2][ch] + a2;
  }
}

// ---------------------------------------------------------------------------
// Mixing kernel v4 (verified r3/r5): LDS-staged mu, 20 KB LDS, no spill.
// VGPR-allocator model (verified r0-r3): cap = f(LDS-implied occupancy).
// 20KB -> 8 blk/CU = 4 waves/SIMD -> cap 128 >= ~90 needed => no spill.
// ---------------------------------------------------------------------------
#define MNPB 8
__global__ __launch_bounds__(128) void mix_kernel(
    const float* __restrict__ Wmix, const float* __restrict__ Wm1,
    const float* __restrict__ bm1, const float* __restrict__ Wm2,
    const float* __restrict__ bm2, float* __restrict__ qout,
    float* __restrict__ muout) {
  __shared__ __align__(16) float mu_lds[MNPB][3][CC];   // 12 KB
  __shared__ __align__(16) float vn_lds[MNPB][CC];      // 4 KB
  __shared__ __align__(16) float h2_lds[MNPB][CC];      // 4 KB

  const int t = threadIdx.x;
  const int node0 = blockIdx.x * MNPB;

  #pragma unroll
  for (int n = 0; n < MNPB; ++n) {
    const size_t mb = (size_t)(node0 + n) * TC;
    mu_lds[n][0][t] = muout[mb + t];
    mu_lds[n][1][t] = muout[mb + CC + t];
    mu_lds[n][2][t] = muout[mb + 2 * CC + t];
  }
  __syncthreads();

  // ---- phase 1: mu_mix from LDS-staged mu ----
  float mW[MNPB][3], sdot[MNPB];
  {
    float mV[MNPB][3];
    #pragma unroll
    for (int n = 0; n < MNPB; ++n)
      #pragma unroll
      for (int v = 0; v < 3; ++v) { mV[n][v] = 0.0f; mW[n][v] = 0.0f; }

    for (int c = 0; c < CC; c += 8) {
      float wv[8], ww[8];
      #pragma unroll
      for (int r = 0; r < 8; ++r) {
        const size_t row = (size_t)(c + r) * (2 * CC);
        wv[r] = Wmix[row + t];
        ww[r] = Wmix[row + CC + t];
      }
      #pragma unroll
      for (int n = 0; n < MNPB; ++n) {
        #pragma unroll
        for (int v = 0; v < 3; ++v) {
          const float4 m0 = *reinterpret_cast<const float4*>(&mu_lds[n][v][c]);
          const float4 m1 = *reinterpret_cast<const float4*>(&mu_lds[n][v][c + 4]);
          float a = mV[n][v], b = mW[n][v];
          a = fmaf(m0.x, wv[0], a); a = fmaf(m0.y, wv[1], a);
          a = fmaf(m0.z, wv[2], a); a = fmaf(m0.w, wv[3], a);
          a = fmaf(m1.x, wv[4], a); a = fmaf(m1.y, wv[5], a);
          a = fmaf(m1.z, wv[6], a); a = fmaf(m1.w, wv[7], a);
          b = fmaf(m0.x, ww[0], b); b = fmaf(m0.y, ww[1], b);
          b = fmaf(m0.z, ww[2], b); b = fmaf(m0.w, ww[3], b);
          b = fmaf(m1.x, ww[4], b); b = fmaf(m1.y, ww[5], b);
          b = fmaf(m1.z, ww[6], b); b = fmaf(m1.w, ww[7], b);
          mV[n][v] = a; mW[n][v] = b;
        }
      }
    }
    #pragma unroll
    for (int n = 0; n < MNPB; ++n) {
      const float ss = mV[n][0] * mV[n][0] + mV[n][1] * mV[n][1] + mV[n][2] * mV[n][2];
      vn_lds[n][t] = sqrtf(ss + 1e-8f);
      sdot[n] = mV[n][0] * mW[n][0] + mV[n][1] * mW[n][1] + mV[n][2] * mW[n][2];
    }
  } // mV dies here
  __syncthreads();   // vn_lds visible

  // ---- phase 2: silu(ctx @ Wm1 + bm1) ----
  float acc[MNPB];
  {
    const float bv = bm1[t];
    #pragma unroll
    for (int n = 0; n < MNPB; ++n) acc[n] = bv;
  }
  // ctx first half: q, wave-uniform broadcast from global (L3-hot)
  for (int k = 0; k < CC; k += 8) {
    float w[8];
    #pragma unroll
    for (int r = 0; r < 8; ++r) w[r] = Wm1[(size_t)(k + r) * CC + t];
    #pragma unroll
    for (int n = 0; n < MNPB; ++n) {
      const float* qrow = qout + (size_t)(node0 + n) * CC + k;
      const float4 c0 = *reinterpret_cast<const float4*>(qrow);
      const float4 c1 = *reinterpret_cast<const float4*>(qrow + 4);
      acc[n] = fmaf(c0.x, w[0], acc[n]); acc[n] = fmaf(c0.y, w[1], acc[n]);
      acc[n] = fmaf(c0.z, w[2], acc[n]); acc[n] = fmaf(c0.w, w[3], acc[n]);
      acc[n] = fmaf(c1.x, w[4], acc[n]); acc[n] = fmaf(c1.y, w[5], acc[n]);
      acc[n] = fmaf(c1.z, w[6], acc[n]); acc[n] = fmaf(c1.w, w[7], acc[n]);
    }
  }
  // ctx second half: mu_Vn from LDS (broadcast)
  for (int k = 0; k < CC; k += 8) {
    float w[8];
    #pragma unroll
    for (int r = 0; r < 8; ++r) w[r] = Wm1[(size_t)(CC + k + r) * CC + t];
    #pragma unroll
    for (int n = 0; n < MNPB; ++n) {
      const float4 c0 = *reinterpret_cast<const float4*>(&vn_lds[n][k]);
      const float4 c1 = *reinterpret_cast<const float4*>(&vn_lds[n][k + 4]);
      acc[n] = fmaf(c0.x, w[0], acc[n]); acc[n] = fmaf(c0.y, w[1], acc[n]);
      acc[n] = fmaf(c0.z, w[2], acc[n]); acc[n] = fmaf(c0.w, w[3], acc[n]);
      acc[n] = fmaf(c1.x, w[4], acc[n]); acc[n] = fmaf(c1.y, w[5], acc[n]);
      acc[n] = fmaf(c1.z, w[6], acc[n]); acc[n] = fmaf(c1.w, w[7], acc[n]);
    }
  }
  #pragma unroll
  for (int n = 0; n < MNPB; ++n) {
    const float v = acc[n];
    h2_lds[n][t] = v / (1.0f + expf(-v));
  }
  __syncthreads();   // h2 visible; all phase-2 broadcast reads of qout done

  // ---- phase 3: y = h2 @ Wm2 + bm2 ----
  float y0[MNPB], y1[MNPB], y2[MNPB];
  {
    const float bb0 = bm2[t], bb1 = bm2[CC + t], bb2 = bm2[2 * CC + t];
    #pragma unroll
    for (int n = 0; n < MNPB; ++n) { y0[n] = bb0; y1[n] = bb1; y2[n] = bb2; }
  }
  for (int k = 0; k < CC; k += 8) {
    float w0[8], w1[8], w2[8];
    #pragma unroll
    for (int r = 0; r < 8; ++r) {
      const size_t row = (size_t)(k + r) * TC;
      w0[r] = Wm2[row + t];
      w1[r] = Wm2[row + CC + t];
      w2[r] = Wm2[row + 2 * CC + t];
    }
    #pragma unroll
    for (int n = 0; n < MNPB; ++n) {
      const float4 h0 = *reinterpret_cast<const float4*>(&h2_lds[n][k]);
      const float4 h1 = *reinterpret_cast<const float4*>(&h2_lds[n][k + 4]);
      y0[n] = fmaf(h0.x, w0[0], y0[n]); y0[n] = fmaf(h0.y, w0[1], y0[n]);
      y0[n] = fmaf(h0.z, w0[2], y0[n]); y0[n] = fmaf(h0.w, w0[3], y0[n]);
      y0[n] = fmaf(h1.x, w0[4], y0[n]); y0[n] = fmaf(h1.y, w0[5], y0[n]);
      y0[n] = fmaf(h1.z, w0[6], y0[n]); y0[n] = fmaf(h1.w, w0[7], y0[n]);
      y1[n] = fmaf(h0.x, w1[0], y1[n]); y1[n] = fmaf(h0.y, w1[1], y1[n]);
      y1[n] = fmaf(h0.z, w1[2], y1[n]); y1[n] = fmaf(h0.w, w1[3], y1[n]);
      y1[n] = fmaf(h1.x, w1[4], y1[n]); y1[n] = fmaf(h1.y, w1[5], y1[n]);
      y1[n] = fmaf(h1.z, w1[6], y1[n]); y1[n] = fmaf(h1.w, w1[7], y1[n]);
      y2[n] = fmaf(h0.x, w2[0], y2[n]); y2[n] = fmaf(h0.y, w2[1], y2[n]);
      y2[n] = fmaf(h0.z, w2[2], y2[n]); y2[n] = fmaf(h0.w, w2[3], y2[n]);
      y2[n] = fmaf(h1.x, w2[4], y2[n]); y2[n] = fmaf(h1.y, w2[5], y2[n]);
      y2[n] = fmaf(h1.z, w2[6], y2[n]); y2[n] = fmaf(h1.w, w2[7], y2[n]);
    }
  }

  // ---- epilogue: q re-read coalesced (L3-hot), mu residual from LDS ----
  #pragma unroll
  for (int n = 0; n < MNPB; ++n) {
    const size_t qb = (size_t)(node0 + n) * CC;
    qout[qb + t] = qout[qb + t] + y0[n] + y2[n] * sdot[n];
    const size_t mb = (size_t)(node0 + n) * TC;
    muout[mb + t]          = mu_lds[n][0][t] + y1[n] * mW[n][0];
    muout[mb + CC + t]     = mu_lds[n][1][t] + y1[n] * mW[n][1];
    muout[mb + 2 * CC + t] = mu_lds[n][2][t] + y1[n] * mW[n][2];
  }
}

// ---------------------------------------------------------------------------
extern "C" void kernel_launch(void* const* d_in, const int* in_sizes, int n_in,
                              void* d_out, int out_size, void* d_ws, size_t ws_size,
                              hipStream_t stream) {
  const float* q     = (const float*)d_in[0];
  const float* mu    = (const float*)d_in[1];
  const int*   eidx  = (const int*)d_in[2];
  const float* ew    = (const float*)d_in[3];
  const float* evers = (const float*)d_in[4];
  const float* eattr = (const float*)d_in[5];
  const float* Wf    = (const float*)d_in[6];
  const float* bf    = (const float*)d_in[7];
  const float* W1    = (const float*)d_in[8];
  const float* b1    = (const float*)d_in[9];
  const float* W2    = (const float*)d_in[10];
  const float* b2    = (const float*)d_in[11];
  const float* Wmix  = (const float*)d_in[12];
  const float* Wm1   = (const float*)d_in[13];
  const float* bm1   = (const float*)d_in[14];
  const float* Wm2   = (const float*)d_in[15];
  const float* bm2   = (const float*)d_in[16];

  float* out   = (float*)d_out;
  float* qout  = out;                                // [N, C]
  float* muout = out + (size_t)NNODES * CC;          // [N, 3, C]

  // workspace layout: packed | xh (fp16) | muh4 (fp16x4) | counts | offsets
  float*  packed  = (float*)d_ws;                             // [E*28] floats
  __half* xh      = (__half*)(packed + (size_t)NEDGES * PKF); // [N*3C] halves
  float2* muh4    = (float2*)(xh + (size_t)NNODES * TC);      // [N*C] 8B words
  int*    counts  = (int*)(muh4 + (size_t)NNODES * CC);       // [N]
  int*    offsets = counts + NNODES;                          // [N+1]
  const size_t need_packed =
      (size_t)NEDGES * PKF * 4 + (size_t)NNODES * TC * 2 +
      (size_t)NNODES * CC * 8 + (2 * NNODES + 2) * 4 + 256;
  const bool use_packed = ws_size >= need_packed;

  if (use_packed) {
    zero_counts_kernel<<<(NNODES + 255) / 256, 256, 0, stream>>>(counts);
    hist_kernel<<<(NEDGES + 255) / 256, 256, 0, stream>>>(eidx, counts);
    scan_kernel<<<1, 512, 0, stream>>>(counts, offsets);
    pack_scatter_kernel<<<(NEDGES + 255) / 256, 256, 0, stream>>>(
        eidx, ew, evers, eattr, offsets, counts, packed);
    mu2h4_kernel<<<(NNODES * CC + 255) / 256, 256, 0, stream>>>(mu, muh4);
    ctx_net_kernel<<<NNODES / CNPB, 128, 0, stream>>>(q, W1, b1, W2, b2, xh);
    gather_packed_kernel<<<NNODES, GTH, 0, stream>>>(
        packed, Wf, bf, xh, muh4, mu, q, offsets, qout, muout);
  } else {
    // fallback layout (xh fp16 | counts | offsets | edge_list)
    __half* xf       = (__half*)d_ws;
    int*   countsf   = (int*)(xf + (size_t)NNODES * TC);
    int*   offsetsf  = countsf + NNODES;
    int*   edge_list = offsetsf + NNODES + 1;
    zero_counts_kernel<<<(NNODES + 255) / 256, 256, 0, stream>>>(countsf);
    hist_kernel<<<(NEDGES + 255) / 256, 256, 0, stream>>>(eidx, countsf);
    scan_kernel<<<1, 512, 0, stream>>>(countsf, offsetsf);
    scatter_kernel<<<(NEDGES + 255) / 256, 256, 0, stream>>>(eidx, offsetsf,
                                                             countsf, edge_list);
    ctx_net_kernel<<<NNODES / CNPB, 128, 0, stream>>>(q, W1, b1, W2, b2, xf);
    gather_list_kernel<<<NNODES, GTH, 0, stream>>>(eidx, ew, evers, eattr,
                                                   Wf, bf, xf, mu, q,
                                                   offsetsf, edge_list,
                                                   qout, muout);
  }
  mix_kernel<<<NNODES / MNPB, 128, 0, stream>>>(Wmix, Wm1, bm1, Wm2, bm2,
                                                qout, muout);
}

// Round 9
// 599.652 us; speedup vs baseline: 1.1032x; 1.0418x over previous
//
#include <hip/hip_runtime.h>
#include <hip/hip_fp16.h>
#include <math.h>

#define NNODES 20000
#define NEDGES 320000
#define CC 128          // channels
#define TC 384          // 3*C
#define BB 20           // basis dim
#define RCUT_F 5.0f
#define PI_F 3.14159265358979323846f
#define PKF 28          // packed floats per edge (112 B, float4-aligned)

// ---------------------------------------------------------------------------
// CSR build: zero -> histogram -> single-block scan -> pack+scatter
// ---------------------------------------------------------------------------
__global__ __launch_bounds__(256) void zero_counts_kernel(int* __restrict__ counts) {
  const int i = blockIdx.x * 256 + threadIdx.x;
  if (i < NNODES) counts[i] = 0;
}

__global__ __launch_bounds__(256) void hist_kernel(const int* __restrict__ eidx,
                                                   int* __restrict__ counts) {
  const int e = blockIdx.x * 256 + threadIdx.x;
  if (e < NEDGES) atomicAdd(&counts[eidx[e]], 1);
}

__global__ __launch_bounds__(512) void scan_kernel(int* __restrict__ counts,
                                                   int* __restrict__ offsets) {
  __shared__ int sums[512];
  const int t = threadIdx.x;
  const int chunk = 40;                       // ceil(20000/512)
  const int lo = t * chunk;
  const int hi = min(lo + chunk, NNODES);
  int s = 0;
  for (int i = lo; i < hi; ++i) s += counts[i];
  sums[t] = s;
  __syncthreads();
  for (int d = 1; d < 512; d <<= 1) {
    const int other = (t >= d) ? sums[t - d] : 0;
    __syncthreads();
    sums[t] += other;
    __syncthreads();
  }
  int run = sums[t] - s;                      // exclusive prefix
  for (int i = lo; i < hi; ++i) {
    offsets[i] = run;
    run += counts[i];
    counts[i] = 0;                            // re-zero: reused as scatter cursor
  }
  if (hi == NNODES) offsets[NNODES] = run;    // == NEDGES
}

// packed[pos] = { j(bits), fc, v0, v1, v2, fc*attrs[0..19], pad[3] }
__global__ __launch_bounds__(256) void pack_scatter_kernel(
    const int* __restrict__ eidx, const float* __restrict__ ew,
    const float* __restrict__ evers, const float* __restrict__ eattr,
    const int* __restrict__ offsets, int* __restrict__ counts,
    float* __restrict__ packed) {
  const int e = blockIdx.x * 256 + threadIdx.x;
  if (e >= NEDGES) return;
  const int i = eidx[e];
  const int j = eidx[NEDGES + e];
  const int pos = offsets[i] + atomicAdd(&counts[i], 1);
  const float w = ew[e];
  const float fc = (w < RCUT_F)
      ? 0.5f * (cosf(PI_F * (1.0f / RCUT_F) * w) + 1.0f) : 0.0f;
  float* p = packed + (size_t)pos * PKF;
  p[0] = __int_as_float(j);
  p[1] = fc;
  p[2] = evers[(size_t)e * 3];
  p[3] = evers[(size_t)e * 3 + 1];
  p[4] = evers[(size_t)e * 3 + 2];
  const float* ae = eattr + (size_t)e * BB;
  #pragma unroll
  for (int b = 0; b < BB; ++b) p[5 + b] = fc * ae[b];
}

// fallback (no packing) scatter for small ws
__global__ __launch_bounds__(256) void scatter_kernel(const int* __restrict__ eidx,
                                                      const int* __restrict__ offsets,
                                                      int* __restrict__ counts,
                                                      int* __restrict__ edge_list) {
  const int e = blockIdx.x * 256 + threadIdx.x;
  if (e < NEDGES) {
    const int i = eidx[e];
    const int pos = offsets[i] + atomicAdd(&counts[i], 1);
    edge_list[pos] = e;
  }
}

// ---------------------------------------------------------------------------
// Context net: x = silu(q@W1 + b1) @ W2 + b2   [N, 3C] (fp16), plus OPTIONAL
// fused fp16 conversion of mu -> muh for this block's 8 nodes (CONVERT_MU=1;
// kills the separate mu2h launch, ~10 us serialized on the stream).
//
// occ_pad: 12 KB LDS pin. ctx_net's natural 8 KB LDS is the exact shape that
// made the allocator cap mix at 48-64 VGPRs and SPILL in r1/r2 (cap =
// f(LDS-implied occupancy), verified r0-r3). Phase 2 here needs ~75 VGPRs
// (24 weights + 24 accumulators + temps); 20 KB total -> 8 blk/CU ->
// 4 waves/SIMD -> cap 128 -> no spill possible. Harmless if it wasn't
// spilling (grid supplies ~10 blocks/CU regardless).
// ---------------------------------------------------------------------------
#define CNPB 8
template <int CONVERT_MU>
__global__ __launch_bounds__(128) void ctx_net_kernel(
    const float* __restrict__ q, const float* __restrict__ mu,
    const float* __restrict__ W1, const float* __restrict__ b1,
    const float* __restrict__ W2, const float* __restrict__ b2,
    __half* __restrict__ x, __half* __restrict__ muh) {
  __shared__ __align__(16) float q_lds[CNPB][CC];
  __shared__ __align__(16) float h_lds[CNPB][CC];
  __shared__ __align__(16) float occ_pad[3072];   // 12 KB occupancy pin
  const int t = threadIdx.x;
  const int node0 = blockIdx.x * CNPB;

  #pragma unroll
  for (int n = 0; n < CNPB; ++n)
    q_lds[n][t] = q[(size_t)(node0 + n) * CC + t];

  if (CONVERT_MU) {
    // fused mu -> fp16 for this block's nodes; independent of LDS, overlaps
    // the q staging + first weight loads
    #pragma unroll
    for (int n = 0; n < CNPB; ++n) {
      const size_t mb = (size_t)(node0 + n) * TC;
      muh[mb + t]          = __float2half_rn(mu[mb + t]);
      muh[mb + CC + t]     = __float2half_rn(mu[mb + CC + t]);
      muh[mb + 2 * CC + t] = __float2half_rn(mu[mb + 2 * CC + t]);
    }
  }

  // keep occ_pad live (never taken at runtime; compiler can't prove it)
  if (blockIdx.x == 0x7FFFFFFFu) {
    occ_pad[t] = q[t];
    x[t] = __float2half_rn(occ_pad[t ^ 1]);
  }
  __syncthreads();

  float acc[CNPB];
  {
    const float bv = b1[t];
    #pragma unroll
    for (int n = 0; n < CNPB; ++n) acc[n] = bv;
  }
  for (int k = 0; k < CC; k += 8) {
    float w[8];
    #pragma unroll
    for (int r = 0; r < 8; ++r) w[r] = W1[(size_t)(k + r) * CC + t];
    #pragma unroll
    for (int n = 0; n < CNPB; ++n) {
      const float4 q0 = *reinterpret_cast<const float4*>(&q_lds[n][k]);
      const float4 q1 = *reinterpret_cast<const float4*>(&q_lds[n][k + 4]);
      acc[n] = fmaf(q0.x, w[0], acc[n]); acc[n] = fmaf(q0.y, w[1], acc[n]);
      acc[n] = fmaf(q0.z, w[2], acc[n]); acc[n] = fmaf(q0.w, w[3], acc[n]);
      acc[n] = fmaf(q1.x, w[4], acc[n]); acc[n] = fmaf(q1.y, w[5], acc[n]);
      acc[n] = fmaf(q1.z, w[6], acc[n]); acc[n] = fmaf(q1.w, w[7], acc[n]);
    }
  }
  #pragma unroll
  for (int n = 0; n < CNPB; ++n) {
    const float v = acc[n];
    h_lds[n][t] = v / (1.0f + expf(-v));
  }
  __syncthreads();

  float y0[CNPB], y1[CNPB], y2[CNPB];
  {
    const float bb0 = b2[t], bb1 = b2[CC + t], bb2 = b2[2 * CC + t];
    #pragma unroll
    for (int n = 0; n < CNPB; ++n) { y0[n] = bb0; y1[n] = bb1; y2[n] = bb2; }
  }
  for (int k = 0; k < CC; k += 8) {
    float w0[8], w1[8], w2[8];
    #pragma unroll
    for (int r = 0; r < 8; ++r) {
      const size_t row = (size_t)(k + r) * TC;
      w0[r] = W2[row + t];
      w1[r] = W2[row + CC + t];
      w2[r] = W2[row + 2 * CC + t];
    }
    #pragma unroll
    for (int n = 0; n < CNPB; ++n) {
      const float4 h0 = *reinterpret_cast<const float4*>(&h_lds[n][k]);
      const float4 h1 = *reinterpret_cast<const float4*>(&h_lds[n][k + 4]);
      y0[n] = fmaf(h0.x, w0[0], y0[n]); y0[n] = fmaf(h0.y, w0[1], y0[n]);
      y0[n] = fmaf(h0.z, w0[2], y0[n]); y0[n] = fmaf(h0.w, w0[3], y0[n]);
      y0[n] = fmaf(h1.x, w0[4], y0[n]); y0[n] = fmaf(h1.y, w0[5], y0[n]);
      y0[n] = fmaf(h1.z, w0[6], y0[n]); y0[n] = fmaf(h1.w, w0[7], y0[n]);
      y1[n] = fmaf(h0.x, w1[0], y1[n]); y1[n] = fmaf(h0.y, w1[1], y1[n]);
      y1[n] = fmaf(h0.z, w1[2], y1[n]); y1[n] = fmaf(h0.w, w1[3], y1[n]);
      y1[n] = fmaf(h1.x, w1[4], y1[n]); y1[n] = fmaf(h1.y, w1[5], y1[n]);
      y1[n] = fmaf(h1.z, w1[6], y1[n]); y1[n] = fmaf(h1.w, w1[7], y1[n]);
      y2[n] = fmaf(h0.x, w2[0], y2[n]); y2[n] = fmaf(h0.y, w2[1], y2[n]);
      y2[n] = fmaf(h0.z, w2[2], y2[n]); y2[n] = fmaf(h0.w, w2[3], y2[n]);
      y2[n] = fmaf(h1.x, w2[4], y2[n]); y2[n] = fmaf(h1.y, w2[5], y2[n]);
      y2[n] = fmaf(h1.z, w2[6], y2[n]); y2[n] = fmaf(h1.w, w2[7], y2[n]);
    }
  }
  #pragma unroll
  for (int n = 0; n < CNPB; ++n) {
    const size_t base = (size_t)(node0 + n) * TC;
    x[base + t]          = __float2half_rn(y0[n]);
    x[base + CC + t]     = __float2half_rn(y1[n]);
    x[base + 2 * CC + t] = __float2half_rn(y2[n]);
  }
}

// ---------------------------------------------------------------------------
// Gather (packed path): one block of 384 threads per node; thread c owns
// filter column c (weights in 20 regs). EXACT r5-verified form (177 us).
// Ledger (all A/B'd against this structure, 6 attempts):
//   r3 x2 fp32 = 186 | r4 manual rotate = 294 (vmcnt(0) drains)
//   r5 x2 fp16 = 177 | r6 x4 unroll = 251 (regs can't hold 4 chains)
//   r7 persistent-1280 = 237 (barrier serialization, no oversubscription)
//   r8 muh4 interleave = 200 (FETCH +39MB, grp2 wasn't critical)
// => 20000 short blocks + x2 body + separate fp16 arrays is the floor of
// this structure. DO NOT touch the inner loop or grid shape.
// ---------------------------------------------------------------------------
#define GTH 384

struct EdgeRegs { float4 h0, h1, h2, h3, h4, h5, h6; };

__device__ __forceinline__ EdgeRegs load_edge(const float4* __restrict__ p4,
                                              int k) {
  const float4* p = p4 + (size_t)k * (PKF / 4);
  EdgeRegs E;
  E.h0 = p[0]; E.h1 = p[1]; E.h2 = p[2]; E.h3 = p[3];
  E.h4 = p[4]; E.h5 = p[5]; E.h6 = p[6];
  return E;
}

__device__ __forceinline__ float filter_ws(const EdgeRegs& E,
                                           const float* wreg, float bfc) {
  float ws = E.h0.y * bfc;                    // fc * bf[c]
  ws = fmaf(E.h1.y, wreg[0], ws);  ws = fmaf(E.h1.z, wreg[1], ws);
  ws = fmaf(E.h1.w, wreg[2], ws);  ws = fmaf(E.h2.x, wreg[3], ws);
  ws = fmaf(E.h2.y, wreg[4], ws);  ws = fmaf(E.h2.z, wreg[5], ws);
  ws = fmaf(E.h2.w, wreg[6], ws);  ws = fmaf(E.h3.x, wreg[7], ws);
  ws = fmaf(E.h3.y, wreg[8], ws);  ws = fmaf(E.h3.z, wreg[9], ws);
  ws = fmaf(E.h3.w, wreg[10], ws); ws = fmaf(E.h4.x, wreg[11], ws);
  ws = fmaf(E.h4.y, wreg[12], ws); ws = fmaf(E.h4.z, wreg[13], ws);
  ws = fmaf(E.h4.w, wreg[14], ws); ws = fmaf(E.h5.x, wreg[15], ws);
  ws = fmaf(E.h5.y, wreg[16], ws); ws = fmaf(E.h5.z, wreg[17], ws);
  ws = fmaf(E.h5.w, wreg[18], ws); ws = fmaf(E.h6.x, wreg[19], ws);
  return ws;
}

__global__ __launch_bounds__(GTH) void gather_packed_kernel(
    const float* __restrict__ packed,
    const float* __restrict__ Wf, const float* __restrict__ bf,
    const __half* __restrict__ xh, const __half* __restrict__ muh,
    const float* __restrict__ mu_in,
    const float* __restrict__ q_in, const int* __restrict__ offsets,
    float* __restrict__ qout, float* __restrict__ muout) {
  __shared__ float red[3][CC];
  const int c = threadIdx.x;
  const int i = blockIdx.x;
  const int grp = c >> 7;          // wave-uniform
  const int ch = c & 127;

  float wreg[BB];
  #pragma unroll
  for (int b = 0; b < BB; ++b) wreg[b] = Wf[b * TC + c];
  const float bfc = bf[c];

  const float4* p4 = reinterpret_cast<const float4*>(packed);
  const int start = offsets[i];
  const int end = offsets[i + 1];
  float a0 = 0.f, a1 = 0.f, a2 = 0.f;

  int k = start;
  for (; k + 1 < end; k += 2) {
    // issue both packed-row loads up front
    const EdgeRegs A = load_edge(p4, k);
    const EdgeRegs B = load_edge(p4, k + 1);
    const int jA = __float_as_int(A.h0.x);
    const int jB = __float_as_int(B.h0.x);
    // both gathers in flight (fp16 rows)
    const float xA = __half2float(xh[(size_t)jA * TC + c]);
    const float xB = __half2float(xh[(size_t)jB * TC + c]);
    float muA0, muA1, muA2, muB0, muB1, muB2;
    if (grp == 2) {
      const __half* mA = muh + (size_t)jA * TC + ch;
      const __half* mB = muh + (size_t)jB * TC + ch;
      muA0 = __half2float(mA[0]);
      muA1 = __half2float(mA[CC]);
      muA2 = __half2float(mA[2 * CC]);
      muB0 = __half2float(mB[0]);
      muB1 = __half2float(mB[CC]);
      muB2 = __half2float(mB[2 * CC]);
    }
    // filter math overlaps the gathers
    const float wsA = filter_ws(A, wreg, bfc);
    const float wsB = filter_ws(B, wreg, bfc);
    const float xvA = xA * wsA;
    const float xvB = xB * wsB;
    if (grp == 0) {
      a0 += xvA + xvB;
    } else if (grp == 1) {
      a0 = fmaf(xvA, A.h0.z, fmaf(xvB, B.h0.z, a0));
      a1 = fmaf(xvA, A.h0.w, fmaf(xvB, B.h0.w, a1));
      a2 = fmaf(xvA, A.h1.x, fmaf(xvB, B.h1.x, a2));
    } else {
      a0 = fmaf(xvA, muA0, fmaf(xvB, muB0, a0));
      a1 = fmaf(xvA, muA1, fmaf(xvB, muB1, a1));
      a2 = fmaf(xvA, muA2, fmaf(xvB, muB2, a2));
    }
  }
  if (k < end) {
    const EdgeRegs A = load_edge(p4, k);
    const int jA = __float_as_int(A.h0.x);
    const float xA = __half2float(xh[(size_t)jA * TC + c]);
    const float wsA = filter_ws(A, wreg, bfc);
    const float xvA = xA * wsA;
    if (grp == 0) {
      a0 += xvA;
    } else if (grp == 1) {
      a0 = fmaf(xvA, A.h0.z, a0);
      a1 = fmaf(xvA, A.h0.w, a1);
      a2 = fmaf(xvA, A.h1.x, a2);
    } else {
      const __half* mA = muh + (size_t)jA * TC + ch;
      a0 = fmaf(xvA, __half2float(mA[0]), a0);
      a1 = fmaf(xvA, __half2float(mA[CC]), a1);
      a2 = fmaf(xvA, __half2float(mA[2 * CC]), a2);
    }
  }

  if (grp == 1) { red[0][ch] = a0; red[1][ch] = a1; red[2][ch] = a2; }
  __syncthreads();

  if (grp == 0) {
    qout[(size_t)i * CC + ch] = q_in[(size_t)i * CC + ch] + a0;
  } else if (grp == 2) {
    const size_t mb = (size_t)i * TC;
    muout[mb + ch]          = mu_in[mb + ch]          + red[0][ch] + a0;
    muout[mb + CC + ch]     = mu_in[mb + CC + ch]     + red[1][ch] + a1;
    muout[mb + 2 * CC + ch] = mu_in[mb + 2 * CC + ch] + red[2][ch] + a2;
  }
}

// fallback gather (edge_list indirection) for small ws
__global__ __launch_bounds__(GTH) void gather_list_kernel(
    const int* __restrict__ eidx, const float* __restrict__ ew,
    const float* __restrict__ evers, const float* __restrict__ eattr,
    const float* __restrict__ Wf, const float* __restrict__ bf,
    const __half* __restrict__ xh, const float* __restrict__ mu_in,
    const float* __restrict__ q_in,
    const int* __restrict__ offsets, const int* __restrict__ edge_list,
    float* __restrict__ qout, float* __restrict__ muout) {
  __shared__ float red[3][CC];
  const int c = threadIdx.x;
  const int i = blockIdx.x;
  const int grp = c >> 7;
  const int ch = c & 127;
  float wreg[BB];
  #pragma unroll
  for (int b = 0; b < BB; ++b) wreg[b] = Wf[b * TC + c];
  const float bfc = bf[c];
  const int start = offsets[i];
  const int end = offsets[i + 1];
  float a0 = 0.f, a1 = 0.f, a2 = 0.f;
  for (int k = start; k < end; ++k) {
    const int e = edge_list[k];
    const int j = eidx[NEDGES + e];
    const float w = ew[e];
    const float fc = (w < RCUT_F)
        ? 0.5f * (cosf(PI_F * (1.0f / RCUT_F) * w) + 1.0f) : 0.0f;
    const float2* ae2 = reinterpret_cast<const float2*>(eattr + (size_t)e * BB);
    float wsum = bfc;
    #pragma unroll
    for (int b = 0; b < BB / 2; ++b) {
      const float2 a = ae2[b];
      wsum = fmaf(a.x, wreg[2 * b], wsum);
      wsum = fmaf(a.y, wreg[2 * b + 1], wsum);
    }
    wsum *= fc;
    const float xv = __half2float(xh[(size_t)j * TC + c]) * wsum;
    if (grp == 0) {
      a0 += xv;
    } else if (grp == 1) {
      const float v0 = evers[(size_t)e * 3];
      const float v1 = evers[(size_t)e * 3 + 1];
      const float v2 = evers[(size_t)e * 3 + 2];
      a0 = fmaf(xv, v0, a0); a1 = fmaf(xv, v1, a1); a2 = fmaf(xv, v2, a2);
    } else {
      const float* muj = mu_in + (size_t)j * TC + ch;
      a0 = fmaf(xv, muj[0], a0);
      a1 = fmaf(xv, muj[CC], a1);
      a2 = fmaf(xv, muj[2 * CC], a2);
    }
  }
  if (grp == 1) { red[0][ch] = a0; red[1][ch] = a1; red[2][ch] = a2; }
  __syncthreads();
  if (grp == 0) {
    qout[(size_t)i * CC + ch] = q_in[(size_t)i * CC + ch] + a0;
  } else if (grp == 2) {
    const size_t mb = (size_t)i * TC;
    muout[mb + ch]          = mu_in[mb + ch]          + red[0][ch] + a0;
    muout[mb + CC + ch]     = mu_in[mb + CC + ch]     + red[1][ch] + a1;
    muout[mb + 2 * CC + ch] = mu_in[mb + 2 * CC + ch] + red[2][ch] + a2;
  }
}

// ---------------------------------------------------------------------------
// Mixing kernel v4 (verified r3/r5): LDS-staged mu, 20 KB LDS, no spill.
// VGPR-allocator model (verified r0-r3): cap = f(LDS-implied occupancy).
// 20KB -> 8 blk/CU = 4 waves/SIMD -> cap 128 >= ~90 needed => no spill.
// ---------------------------------------------------------------------------
#define MNPB 8
__global__ __launch_bounds__(128) void mix_kernel(
    const float* __restrict__ Wmix, const float* __restrict__ Wm1,
    const float* __restrict__ bm1, const float* __restrict__ Wm2,
    const float* __restrict__ bm2, float* __restrict__ qout,
    float* __restrict__ muout) {
  __shared__ __align__(16) float mu_lds[MNPB][3][CC];   // 12 KB
  __shared__ __align__(16) float vn_lds[MNPB][CC];      // 4 KB
  __shared__ __align__(16) float h2_lds[MNPB][CC];      // 4 KB

  const int t = threadIdx.x;
  const int node0 = blockIdx.x * MNPB;

  #pragma unroll
  for (int n = 0; n < MNPB; ++n) {
    const size_t mb = (size_t)(node0 + n) * TC;
    mu_lds[n][0][t] = muout[mb + t];
    mu_lds[n][1][t] = muout[mb + CC + t];
    mu_lds[n][2][t] = muout[mb + 2 * CC + t];
  }
  __syncthreads();

  // ---- phase 1: mu_mix from LDS-staged mu ----
  float mW[MNPB][3], sdot[MNPB];
  {
    float mV[MNPB][3];
    #pragma unroll
    for (int n = 0; n < MNPB; ++n)
      #pragma unroll
      for (int v = 0; v < 3; ++v) { mV[n][v] = 0.0f; mW[n][v] = 0.0f; }

    for (int c = 0; c < CC; c += 8) {
      float wv[8], ww[8];
      #pragma unroll
      for (int r = 0; r < 8; ++r) {
        const size_t row = (size_t)(c + r) * (2 * CC);
        wv[r] = Wmix[row + t];
        ww[r] = Wmix[row + CC + t];
      }
      #pragma unroll
      for (int n = 0; n < MNPB; ++n) {
        #pragma unroll
        for (int v = 0; v < 3; ++v) {
          const float4 m0 = *reinterpret_cast<const float4*>(&mu_lds[n][v][c]);
          const float4 m1 = *reinterpret_cast<const float4*>(&mu_lds[n][v][c + 4]);
          float a = mV[n][v], b = mW[n][v];
          a = fmaf(m0.x, wv[0], a); a = fmaf(m0.y, wv[1], a);
          a = fmaf(m0.z, wv[2], a); a = fmaf(m0.w, wv[3], a);
          a = fmaf(m1.x, wv[4], a); a = fmaf(m1.y, wv[5], a);
          a = fmaf(m1.z, wv[6], a); a = fmaf(m1.w, wv[7], a);
          b = fmaf(m0.x, ww[0], b); b = fmaf(m0.y, ww[1], b);
          b = fmaf(m0.z, ww[2], b); b = fmaf(m0.w, ww[3], b);
          b = fmaf(m1.x, ww[4], b); b = fmaf(m1.y, ww[5], b);
          b = fmaf(m1.z, ww[6], b); b = fmaf(m1.w, ww[7], b);
          mV[n][v] = a; mW[n][v] = b;
        }
      }
    }
    #pragma unroll
    for (int n = 0; n < MNPB; ++n) {
      const float ss = mV[n][0] * mV[n][0] + mV[n][1] * mV[n][1] + mV[n][2] * mV[n][2];
      vn_lds[n][t] = sqrtf(ss + 1e-8f);
      sdot[n] = mV[n][0] * mW[n][0] + mV[n][1] * mW[n][1] + mV[n][2] * mW[n][2];
    }
  } // mV dies here
  __syncthreads();   // vn_lds visible

  // ---- phase 2: silu(ctx @ Wm1 + bm1) ----
  float acc[MNPB];
  {
    const float bv = bm1[t];
    #pragma unroll
    for (int n = 0; n < MNPB; ++n) acc[n] = bv;
  }
  // ctx first half: q, wave-uniform broadcast from global (L3-hot)
  for (int k = 0; k < CC; k += 8) {
    float w[8];
    #pragma unroll
    for (int r = 0; r < 8; ++r) w[r] = Wm1[(size_t)(k + r) * CC + t];
    #pragma unroll
    for (int n = 0; n < MNPB; ++n) {
      const float* qrow = qout + (size_t)(node0 + n) * CC + k;
      const float4 c0 = *reinterpret_cast<const float4*>(qrow);
      const float4 c1 = *reinterpret_cast<const float4*>(qrow + 4);
      acc[n] = fmaf(c0.x, w[0], acc[n]); acc[n] = fmaf(c0.y, w[1], acc[n]);
      acc[n] = fmaf(c0.z, w[2], acc[n]); acc[n] = fmaf(c0.w, w[3], acc[n]);
      acc[n] = fmaf(c1.x, w[4], acc[n]); acc[n] = fmaf(c1.y, w[5], acc[n]);
      acc[n] = fmaf(c1.z, w[6], acc[n]); acc[n] = fmaf(c1.w, w[7], acc[n]);
    }
  }
  // ctx second half: mu_Vn from LDS (broadcast)
  for (int k = 0; k < CC; k += 8) {
    float w[8];
    #pragma unroll
    for (int r = 0; r < 8; ++r) w[r] = Wm1[(size_t)(CC + k + r) * CC + t];
    #pragma unroll
    for (int n = 0; n < MNPB; ++n) {
      const float4 c0 = *reinterpret_cast<const float4*>(&vn_lds[n][k]);
      const float4 c1 = *reinterpret_cast<const float4*>(&vn_lds[n][k + 4]);
      acc[n] = fmaf(c0.x, w[0], acc[n]); acc[n] = fmaf(c0.y, w[1], acc[n]);
      acc[n] = fmaf(c0.z, w[2], acc[n]); acc[n] = fmaf(c0.w, w[3], acc[n]);
      acc[n] = fmaf(c1.x, w[4], acc[n]); acc[n] = fmaf(c1.y, w[5], acc[n]);
      acc[n] = fmaf(c1.z, w[6], acc[n]); acc[n] = fmaf(c1.w, w[7], acc[n]);
    }
  }
  #pragma unroll
  for (int n = 0; n < MNPB; ++n) {
    const float v = acc[n];
    h2_lds[n][t] = v / (1.0f + expf(-v));
  }
  __syncthreads();   // h2 visible; all phase-2 broadcast reads of qout done

  // ---- phase 3: y = h2 @ Wm2 + bm2 ----
  float y0[MNPB], y1[MNPB], y2[MNPB];
  {
    const float bb0 = bm2[t], bb1 = bm2[CC + t], bb2 = bm2[2 * CC + t];
    #pragma unroll
    for (int n = 0; n < MNPB; ++n) { y0[n] = bb0; y1[n] = bb1; y2[n] = bb2; }
  }
  for (int k = 0; k < CC; k += 8) {
    float w0[8], w1[8], w2[8];
    #pragma unroll
    for (int r = 0; r < 8; ++r) {
      const size_t row = (size_t)(k + r) * TC;
      w0[r] = Wm2[row + t];
      w1[r] = Wm2[row + CC + t];
      w2[r] = Wm2[row + 2 * CC + t];
    }
    #pragma unroll
    for (int n = 0; n < MNPB; ++n) {
      const float4 h0 = *reinterpret_cast<const float4*>(&h2_lds[n][k]);
      const float4 h1 = *reinterpret_cast<const float4*>(&h2_lds[n][k + 4]);
      y0[n] = fmaf(h0.x, w0[0], y0[n]); y0[n] = fmaf(h0.y, w0[1], y0[n]);
      y0[n] = fmaf(h0.z, w0[2], y0[n]); y0[n] = fmaf(h0.w, w0[3], y0[n]);
      y0[n] = fmaf(h1.x, w0[4], y0[n]); y0[n] = fmaf(h1.y, w0[5], y0[n]);
      y0[n] = fmaf(h1.z, w0[6], y0[n]); y0[n] = fmaf(h1.w, w0[7], y0[n]);
      y1[n] = fmaf(h0.x, w1[0], y1[n]); y1[n] = fmaf(h0.y, w1[1], y1[n]);
      y1[n] = fmaf(h0.z, w1[2], y1[n]); y1[n] = fmaf(h0.w, w1[3], y1[n]);
      y1[n] = fmaf(h1.x, w1[4], y1[n]); y1[n] = fmaf(h1.y, w1[5], y1[n]);
      y1[n] = fmaf(h1.z, w1[6], y1[n]); y1[n] = fmaf(h1.w, w1[7], y1[n]);
      y2[n] = fmaf(h0.x, w2[0], y2[n]); y2[n] = fmaf(h0.y, w2[1], y2[n]);
      y2[n] = fmaf(h0.z, w2[2], y2[n]); y2[n] = fmaf(h0.w, w2[3], y2[n]);
      y2[n] = fmaf(h1.x, w2[4], y2[n]); y2[n] = fmaf(h1.y, w2[5], y2[n]);
      y2[n] = fmaf(h1.z, w2[6], y2[n]); y2[n] = fmaf(h1.w, w2[7], y2[n]);
    }
  }

  // ---- epilogue: q re-read coalesced (L3-hot), mu residual from LDS ----
  #pragma unroll
  for (int n = 0; n < MNPB; ++n) {
    const size_t qb = (size_t)(node0 + n) * CC;
    qout[qb + t] = qout[qb + t] + y0[n] + y2[n] * sdot[n];
    const size_t mb = (size_t)(node0 + n) * TC;
    muout[mb + t]          = mu_lds[n][0][t] + y1[n] * mW[n][0];
    muout[mb + CC + t]     = mu_lds[n][1][t] + y1[n] * mW[n][1];
    muout[mb + 2 * CC + t] = mu_lds[n][2][t] + y1[n] * mW[n][2];
  }
}

// ---------------------------------------------------------------------------
extern "C" void kernel_launch(void* const* d_in, const int* in_sizes, int n_in,
                              void* d_out, int out_size, void* d_ws, size_t ws_size,
                              hipStream_t stream) {
  const float* q     = (const float*)d_in[0];
  const float* mu    = (const float*)d_in[1];
  const int*   eidx  = (const int*)d_in[2];
  const float* ew    = (const float*)d_in[3];
  const float* evers = (const float*)d_in[4];
  const float* eattr = (const float*)d_in[5];
  const float* Wf    = (const float*)d_in[6];
  const float* bf    = (const float*)d_in[7];
  const float* W1    = (const float*)d_in[8];
  const float* b1    = (const float*)d_in[9];
  const float* W2    = (const float*)d_in[10];
  const float* b2    = (const float*)d_in[11];
  const float* Wmix  = (const float*)d_in[12];
  const float* Wm1   = (const float*)d_in[13];
  const float* bm1   = (const float*)d_in[14];
  const float* Wm2   = (const float*)d_in[15];
  const float* bm2   = (const float*)d_in[16];

  float* out   = (float*)d_out;
  float* qout  = out;                                // [N, C]
  float* muout = out + (size_t)NNODES * CC;          // [N, 3, C]

  // workspace layout: packed | xh (fp16) | muh (fp16) | counts | offsets
  float*  packed  = (float*)d_ws;                           // [E*28] floats
  __half* xh      = (__half*)(packed + (size_t)NEDGES * PKF);   // [N*3C] halves
  __half* muh     = xh + (size_t)NNODES * TC;                   // [N*3C] halves
  int*    counts  = (int*)(muh + (size_t)NNODES * TC);      // [N]
  int*    offsets = counts + NNODES;                        // [N+1]
  const size_t need_packed =
      (size_t)NEDGES * PKF * 4 + (size_t)NNODES * TC * 2 * 2 +
      (2 * NNODES + 2) * 4 + 256;
  const bool use_packed = ws_size >= need_packed;

  if (use_packed) {
    zero_counts_kernel<<<(NNODES + 255) / 256, 256, 0, stream>>>(counts);
    hist_kernel<<<(NEDGES + 255) / 256, 256, 0, stream>>>(eidx, counts);
    scan_kernel<<<1, 512, 0, stream>>>(counts, offsets);
    pack_scatter_kernel<<<(NEDGES + 255) / 256, 256, 0, stream>>>(
        eidx, ew, evers, eattr, offsets, counts, packed);
    ctx_net_kernel<1><<<NNODES / CNPB, 128, 0, stream>>>(q, mu, W1, b1, W2, b2,
                                                         xh, muh);
    gather_packed_kernel<<<NNODES, GTH, 0, stream>>>(
        packed, Wf, bf, xh, muh, mu, q, offsets, qout, muout);
  } else {
    // fallback layout (xh fp16 | counts | offsets | edge_list); no muh --
    // ctx_net<0> skips the conversion, gather_list reads fp32 mu.
    __half* xf       = (__half*)d_ws;
    int*   countsf   = (int*)(xf + (size_t)NNODES * TC);
    int*   offsetsf  = countsf + NNODES;
    int*   edge_list = offsetsf + NNODES + 1;
    zero_counts_kernel<<<(NNODES + 255) / 256, 256, 0, stream>>>(countsf);
    hist_kernel<<<(NEDGES + 255) / 256, 256, 0, stream>>>(eidx, countsf);
    scan_kernel<<<1, 512, 0, stream>>>(countsf, offsetsf);
    scatter_kernel<<<(NEDGES + 255) / 256, 256, 0, stream>>>(eidx, offsetsf,
                                                             countsf, edge_list);
    ctx_net_kernel<0><<<NNODES / CNPB, 128, 0, stream>>>(q, mu, W1, b1, W2, b2,
                                                         xf, nullptr);
    gather_list_kernel<<<NNODES, GTH, 0, stream>>>(eidx, ew, evers, eattr,
                                                   Wf, bf, xf, mu, q,
                                                   offsetsf, edge_list,
                                                   qout, muout);
  }
  mix_kernel<<<NNODES / MNPB, 128, 0, stream>>>(Wmix, Wm1, bm1, Wm2, bm2,
                                                qout, muout);
}